// Round 2
// baseline (434.855 us; speedup 1.0000x reference)
//
#include <hip/hip_runtime.h>
#include <hip/hip_bf16.h>
#include <cmath>

// Problem constants
#define HIDDEN 2048
#define SEQ 2048
#define BATCH 2
#define NQ 16
#define NKV 8
#define HD 128
#define RANKL 8
#define LORA_SCALE 2.0f
#define INV_SQRT_D 0.08838834764831845f
#define LOG2E 1.4426950408889634f
#define SM_SCALE (INV_SQRT_D * LOG2E)

typedef unsigned short ushort_t;
typedef __bf16 bf16x8 __attribute__((ext_vector_type(8)));
typedef float f32x4 __attribute__((ext_vector_type(4)));

static __device__ __forceinline__ ushort_t f2bf(float f) {
    __hip_bfloat16 h = __float2bfloat16(f);
    return *(ushort_t*)&h;
}
static __device__ __forceinline__ float bf2f(ushort_t u) {
    unsigned int v = ((unsigned int)u) << 16;
    return __builtin_bit_cast(float, v);
}
static __device__ __forceinline__ void gload_lds16(const ushort_t* g, ushort_t* l) {
    __builtin_amdgcn_global_load_lds(
        (const __attribute__((address_space(1))) unsigned int*)g,
        (__attribute__((address_space(3))) unsigned int*)l, 16, 0, 0);
}

// ---------------------------------------------------------------------------
// Fused: cast x row to bf16 + LoRA A-projections for q,k,v. One block/row.
// ---------------------------------------------------------------------------
__global__ __launch_bounds__(256) void lora_cast_x(
    const float* __restrict__ X, ushort_t* __restrict__ Xbf,
    const float* __restrict__ qA, const float* __restrict__ kA,
    const float* __restrict__ vA,
    float* __restrict__ oq, float* __restrict__ ok, float* __restrict__ ov)
{
    int m = blockIdx.x;
    int t = threadIdx.x;
    int c0 = t * 8;
    const float* xr = X + (size_t)m * HIDDEN + c0;
    float4 a = *(const float4*)xr;
    float4 b = *(const float4*)(xr + 4);
    float xv[8] = {a.x, a.y, a.z, a.w, b.x, b.y, b.z, b.w};
    uint4 o;
    o.x = (unsigned int)f2bf(xv[0]) | ((unsigned int)f2bf(xv[1]) << 16);
    o.y = (unsigned int)f2bf(xv[2]) | ((unsigned int)f2bf(xv[3]) << 16);
    o.z = (unsigned int)f2bf(xv[4]) | ((unsigned int)f2bf(xv[5]) << 16);
    o.w = (unsigned int)f2bf(xv[6]) | ((unsigned int)f2bf(xv[7]) << 16);
    *(uint4*)(Xbf + (size_t)m * HIDDEN + c0) = o;

    float p[3][RANKL];
#pragma unroll
    for (int w = 0; w < 3; w++)
#pragma unroll
        for (int r = 0; r < RANKL; r++) p[w][r] = 0.f;
    const float* Aw[3] = {qA, kA, vA};
#pragma unroll
    for (int e = 0; e < 8; e++) {
        float x8 = xv[e];
#pragma unroll
        for (int w = 0; w < 3; w++)
#pragma unroll
            for (int r = 0; r < RANKL; r++)
                p[w][r] += x8 * Aw[w][r * HIDDEN + c0 + e];
    }
#pragma unroll
    for (int w = 0; w < 3; w++)
#pragma unroll
        for (int r = 0; r < RANKL; r++) {
            float v = p[w][r];
            v += __shfl_xor(v, 32); v += __shfl_xor(v, 16);
            v += __shfl_xor(v, 8);  v += __shfl_xor(v, 4);
            v += __shfl_xor(v, 2);  v += __shfl_xor(v, 1);
            p[w][r] = v;
        }
    __shared__ float wred[4][3][RANKL];
    int wave = t >> 6, lane = t & 63;
    if (lane == 0) {
#pragma unroll
        for (int w = 0; w < 3; w++)
#pragma unroll
            for (int r = 0; r < RANKL; r++) wred[wave][w][r] = p[w][r];
    }
    __syncthreads();
    if (t < 3 * RANKL) {
        int w = t / RANKL, r = t % RANKL;
        float s = wred[0][w][r] + wred[1][w][r] + wred[2][w][r] + wred[3][w][r];
        float* dst = (w == 0) ? oq : (w == 1) ? ok : ov;
        dst[(size_t)m * RANKL + r] = s;
    }
}

// bf16-input LoRA A-projection (for o)
__global__ __launch_bounds__(256) void lora_xa_bf16(
    const ushort_t* __restrict__ X, const float* __restrict__ Aw,
    float* __restrict__ out, int K)
{
    int m = blockIdx.x;
    int t = threadIdx.x;
    const ushort_t* xr = X + (size_t)m * K;
    float p[RANKL];
#pragma unroll
    for (int r = 0; r < RANKL; r++) p[r] = 0.f;
    for (int c = t; c < K; c += 256) {
        float xv = bf2f(xr[c]);
#pragma unroll
        for (int r = 0; r < RANKL; r++) p[r] += xv * Aw[r * K + c];
    }
#pragma unroll
    for (int r = 0; r < RANKL; r++) {
        float v = p[r];
        v += __shfl_xor(v, 32); v += __shfl_xor(v, 16);
        v += __shfl_xor(v, 8);  v += __shfl_xor(v, 4);
        v += __shfl_xor(v, 2);  v += __shfl_xor(v, 1);
        p[r] = v;
    }
    __shared__ float wred[4][RANKL];
    int wave = t >> 6, lane = t & 63;
    if (lane == 0) {
#pragma unroll
        for (int r = 0; r < RANKL; r++) wred[wave][r] = p[r];
    }
    __syncthreads();
    if (t < RANKL) {
        out[(size_t)m * RANKL + t] =
            wred[0][t] + wred[1][t] + wred[2][t] + wred[3][t];
    }
}

// ---------------------------------------------------------------------------
// All four weight casts in one kernel. Chunks of 8 elements.
// ---------------------------------------------------------------------------
__global__ __launch_bounds__(256) void cast_weights(
    const float* __restrict__ Wq, const float* __restrict__ Wk,
    const float* __restrict__ Wv, const float* __restrict__ Wo,
    ushort_t* __restrict__ Wqb, ushort_t* __restrict__ Wkb,
    ushort_t* __restrict__ Wvb, ushort_t* __restrict__ Wob)
{
    size_t i = (size_t)blockIdx.x * 256 + threadIdx.x;   // 0..1572863
    const float* src; ushort_t* dst; size_t j;
    if (i < 524288)       { src = Wq; dst = Wqb; j = i; }
    else if (i < 786432)  { src = Wk; dst = Wkb; j = i - 524288; }
    else if (i < 1048576) { src = Wv; dst = Wvb; j = i - 786432; }
    else                  { src = Wo; dst = Wob; j = i - 1048576; }
    const float4* p = (const float4*)src + j * 2;
    float4 a = p[0], b = p[1];
    uint4 o;
    o.x = (unsigned int)f2bf(a.x) | ((unsigned int)f2bf(a.y) << 16);
    o.y = (unsigned int)f2bf(a.z) | ((unsigned int)f2bf(a.w) << 16);
    o.z = (unsigned int)f2bf(b.x) | ((unsigned int)f2bf(b.y) << 16);
    o.w = (unsigned int)f2bf(b.z) | ((unsigned int)f2bf(b.w) << 16);
    *(uint4*)(dst + j * 8) = o;
}

// ---------------------------------------------------------------------------
// bf16 MFMA GEMM core (m97 structure, 128x128 tile) -- kept for gemm_wo.
// ---------------------------------------------------------------------------
static __device__ __forceinline__ void gemm_core(
    const ushort_t* __restrict__ A, const ushort_t* __restrict__ B,
    void* __restrict__ Cout, int N, int K, int bm, int bn,
    const float* __restrict__ xa, const float* __restrict__ LB,
    float lscale, int out_bf16, ushort_t* As, ushort_t* Bs)
{
    const int t = threadIdx.x;
    const int lane = t & 63;
    const int w = t >> 6;
    const int quad = lane >> 4;
    const int c = lane & 15;

    const int wm = (w & 1) * 64;
    const int wn = (w >> 1) * 64;

    f32x4 acc[4][4];
#pragma unroll
    for (int i = 0; i < 4; i++)
#pragma unroll
        for (int j = 0; j < 4; j++) acc[i][j] = (f32x4){0.f, 0.f, 0.f, 0.f};

    const int p0 = w * 64 + lane;
    const int p1 = 256 + w * 64 + lane;
    const int r0 = p0 >> 2, g0 = (p0 & 3) ^ ((p0 >> 3) & 3);
    const int r1 = p1 >> 2, g1 = (p1 & 3) ^ ((p1 >> 3) & 3);
    const ushort_t* gA0 = A + (size_t)(bm + r0) * K + g0 * 8;
    const ushort_t* gA1 = A + (size_t)(bm + r1) * K + g1 * 8;
    const ushort_t* gB0 = B + (size_t)(bn + r0) * K + g0 * 8;
    const ushort_t* gB1 = B + (size_t)(bn + r1) * K + g1 * 8;
    ushort_t* lA0 = As + (size_t)(w * 64) * 8;
    ushort_t* lA1 = As + (size_t)(256 + w * 64) * 8;
    ushort_t* lB0 = Bs + (size_t)(w * 64) * 8;
    ushort_t* lB1 = Bs + (size_t)(256 + w * 64) * 8;

    const int csw = quad ^ ((c >> 1) & 3);

    for (int k0 = 0; k0 < K; k0 += 32) {
        __syncthreads();
        gload_lds16(gA0 + k0, lA0);
        gload_lds16(gA1 + k0, lA1);
        gload_lds16(gB0 + k0, lB0);
        gload_lds16(gB1 + k0, lB1);
        __syncthreads();

        bf16x8 af[4], bfr[4];
#pragma unroll
        for (int mt = 0; mt < 4; mt++)
            af[mt] = *(const bf16x8*)&As[((wm + mt * 16 + c) * 4 + csw) * 8];
#pragma unroll
        for (int nt = 0; nt < 4; nt++)
            bfr[nt] = *(const bf16x8*)&Bs[((wn + nt * 16 + c) * 4 + csw) * 8];
#pragma unroll
        for (int mt = 0; mt < 4; mt++)
#pragma unroll
            for (int nt = 0; nt < 4; nt++)
                acc[mt][nt] = __builtin_amdgcn_mfma_f32_16x16x32_bf16(
                    af[mt], bfr[nt], acc[mt][nt], 0, 0, 0);
    }

    float lb[4][RANKL];
#pragma unroll
    for (int nt = 0; nt < 4; nt++) {
        int col = bn + wn + nt * 16 + c;
        float4 u = *(const float4*)&LB[(size_t)col * RANKL];
        float4 v = *(const float4*)&LB[(size_t)col * RANKL + 4];
        lb[nt][0] = u.x; lb[nt][1] = u.y; lb[nt][2] = u.z; lb[nt][3] = u.w;
        lb[nt][4] = v.x; lb[nt][5] = v.y; lb[nt][6] = v.z; lb[nt][7] = v.w;
    }
#pragma unroll
    for (int mt = 0; mt < 4; mt++) {
        float la[4][RANKL];
#pragma unroll
        for (int r = 0; r < 4; r++) {
            int row = bm + wm + mt * 16 + quad * 4 + r;
            float4 u = *(const float4*)&xa[(size_t)row * RANKL];
            float4 v = *(const float4*)&xa[(size_t)row * RANKL + 4];
            la[r][0] = u.x; la[r][1] = u.y; la[r][2] = u.z; la[r][3] = u.w;
            la[r][4] = v.x; la[r][5] = v.y; la[r][6] = v.z; la[r][7] = v.w;
        }
#pragma unroll
        for (int nt = 0; nt < 4; nt++) {
#pragma unroll
            for (int r = 0; r < 4; r++) {
                float s = 0.f;
#pragma unroll
                for (int k = 0; k < RANKL; k++) s += la[r][k] * lb[nt][k];
                float val = acc[mt][nt][r] + lscale * s;
                size_t row = bm + wm + mt * 16 + quad * 4 + r;
                size_t col = bn + wn + nt * 16 + c;
                if (out_bf16)
                    ((ushort_t*)Cout)[row * N + col] = f2bf(val);
                else
                    ((float*)Cout)[row * N + col] = val;
            }
        }
    }
}

// ---------------------------------------------------------------------------
// 256x256-tile 8-wave deep-pipelined QKV GEMM (T2+T3+T4+T5).
// ---------------------------------------------------------------------------
#define BKT 64
#define NKT (HIDDEN / BKT)   // 32

__global__ __launch_bounds__(512, 2) void gemm_qkv256(
    const ushort_t* __restrict__ A,
    const ushort_t* __restrict__ Wqb, const ushort_t* __restrict__ Wkb,
    const ushort_t* __restrict__ Wvb,
    ushort_t* __restrict__ q_lin, ushort_t* __restrict__ k_lin,
    ushort_t* __restrict__ v_lin,
    const float* __restrict__ xa_q, const float* __restrict__ xa_k,
    const float* __restrict__ xa_v,
    const float* __restrict__ qB, const float* __restrict__ kB,
    const float* __restrict__ vB)
{
    __shared__ __align__(16) ushort_t As[2][256 * BKT];   // 64 KiB
    __shared__ __align__(16) ushort_t Bs[2][256 * BKT];   // 64 KiB

    const int t = threadIdx.x;
    const int lane = t & 63;
    const int w = t >> 6;          // 0..7
    const int wm = w >> 2;         // 0..1  (M half)
    const int wn = w & 3;          // 0..3  (N quarter)
    const int quad = lane >> 4;
    const int c = lane & 15;
    const int c7 = c & 7;

    const int bc = blockIdx.y;
    const ushort_t* Bmat; ushort_t* Cout; const float* xa; const float* LB;
    int N, bn;
    if (bc < 8)       { Bmat = Wqb; Cout = q_lin; xa = xa_q; LB = qB; N = 2048; bn = bc * 256; }
    else if (bc < 12) { Bmat = Wkb; Cout = k_lin; xa = xa_k; LB = kB; N = 1024; bn = (bc - 8) * 256; }
    else              { Bmat = Wvb; Cout = v_lin; xa = xa_v; LB = vB; N = 1024; bn = (bc - 12) * 256; }
    const int bm = blockIdx.x * 256;

    // ---- staging addressing (chunk-XOR involution, linear LDS dest)
    const int r8  = lane >> 3;           // 0..7 row within 8-row group
    const int ksl = (lane & 7) ^ r8;     // swizzled k-chunk for this lane
    const int ga  = wn;                  // index within A staging group (wm)
    const int bh  = wn >> 1;             // B half this wave consumes
    const int gb  = wm * 2 + (wn & 1);   // index within B staging group (bh)

    const ushort_t* gAb = A    + (size_t)(bm + wm * 128 + ga * 8 + r8) * HIDDEN + ksl * 8;
    const ushort_t* gBb = Bmat + (size_t)(bn + bh * 128 + gb * 8 + r8) * HIDDEN + ksl * 8;
    const int lAoff = (wm * 128 + ga * 8) * BKT;   // + j*32*BKT
    const int lBoff = (bh * 128 + gb * 8) * BKT;

    // ---- prologue: tile 0 fully, tile 1 parts j=0..2
#pragma unroll
    for (int j = 0; j < 4; j++) {
        gload_lds16(gAb + (size_t)j * 32 * HIDDEN, &As[0][lAoff + j * 32 * BKT]);
        gload_lds16(gBb + (size_t)j * 32 * HIDDEN, &Bs[0][lBoff + j * 32 * BKT]);
    }
#pragma unroll
    for (int j = 0; j < 3; j++) {
        gload_lds16(gAb + (size_t)j * 32 * HIDDEN + BKT, &As[1][lAoff + j * 32 * BKT]);
        gload_lds16(gBb + (size_t)j * 32 * HIDDEN + BKT, &Bs[1][lBoff + j * 32 * BKT]);
    }

    f32x4 acc[8][4];
#pragma unroll
    for (int i = 0; i < 8; i++)
#pragma unroll
        for (int j = 0; j < 4; j++) acc[i][j] = (f32x4){0.f, 0.f, 0.f, 0.f};

#pragma unroll 1
    for (int T = 0; T < NKT; ++T) {
        const int cur = T & 1;
        const ushort_t* cA = As[cur];
        const ushort_t* cB = Bs[cur];
        bf16x8 bfr[4][2];

#pragma unroll
        for (int q = 0; q < 4; ++q) {
            if (q == 0) {
                asm volatile("s_waitcnt vmcnt(6)" ::: "memory");
            }
            __builtin_amdgcn_sched_barrier(0);
            __builtin_amdgcn_s_barrier();
            __builtin_amdgcn_sched_barrier(0);

            // ---- ds reads: A quadrant q (4 x b128); B all (8 x b128) at q==0
            bf16x8 af[2][2];
#pragma unroll
            for (int m2 = 0; m2 < 2; ++m2) {
                const int row = wm * 128 + (q * 2 + m2) * 16 + c;
#pragma unroll
                for (int kh = 0; kh < 2; ++kh)
                    af[m2][kh] = *(const bf16x8*)
                        &cA[row * BKT + (((kh * 4 + quad) ^ c7) * 8)];
            }
            if (q == 0) {
#pragma unroll
                for (int nt = 0; nt < 4; ++nt) {
                    const int rowb = wn * 64 + nt * 16 + c;
#pragma unroll
                    for (int kh = 0; kh < 2; ++kh)
                        bfr[nt][kh] = *(const bf16x8*)
                            &cB[rowb * BKT + (((kh * 4 + quad) ^ c7) * 8)];
                }
            }

            // ---- staging
            if (q == 0) {
                const int tl = T + 1;
                if (tl < NKT) {
                    gload_lds16(gAb + (size_t)3 * 32 * HIDDEN + (size_t)tl * BKT,
                                &As[cur ^ 1][lAoff + 3 * 32 * BKT]);
                    gload_lds16(gBb + (size_t)3 * 32 * HIDDEN + (size_t)tl * BKT,
                                &Bs[cur ^ 1][lBoff + 3 * 32 * BKT]);
                }
            } else {
                const int tl = T + 2;
                if (tl < NKT) {
                    const int j = q - 1;
                    gload_lds16(gAb + (size_t)j * 32 * HIDDEN + (size_t)tl * BKT,
                                &As[cur][lAoff + j * 32 * BKT]);
                    gload_lds16(gBb + (size_t)j * 32 * HIDDEN + (size_t)tl * BKT,
                                &Bs[cur][lBoff + j * 32 * BKT]);
                }
            }

            // ---- 16 MFMA: C-quadrant (32 rows x 64 cols) over K=64
            __builtin_amdgcn_s_setprio(1);
#pragma unroll
            for (int m2 = 0; m2 < 2; ++m2)
#pragma unroll
                for (int nt = 0; nt < 4; ++nt)
#pragma unroll
                    for (int kh = 0; kh < 2; ++kh)
                        acc[q * 2 + m2][nt] = __builtin_amdgcn_mfma_f32_16x16x32_bf16(
                            af[m2][kh], bfr[nt][kh], acc[q * 2 + m2][nt], 0, 0, 0);
            __builtin_amdgcn_s_setprio(0);
        }
    }

    // ---- epilogue: fused LoRA rank-8 + bf16 store
    float lb[4][RANKL];
#pragma unroll
    for (int nt = 0; nt < 4; nt++) {
        int col = bn + wn * 64 + nt * 16 + c;
        float4 u = *(const float4*)&LB[(size_t)col * RANKL];
        float4 v = *(const float4*)&LB[(size_t)col * RANKL + 4];
        lb[nt][0] = u.x; lb[nt][1] = u.y; lb[nt][2] = u.z; lb[nt][3] = u.w;
        lb[nt][4] = v.x; lb[nt][5] = v.y; lb[nt][6] = v.z; lb[nt][7] = v.w;
    }
#pragma unroll
    for (int mt = 0; mt < 8; mt++) {
        float la[4][RANKL];
#pragma unroll
        for (int r = 0; r < 4; r++) {
            int row = bm + wm * 128 + mt * 16 + quad * 4 + r;
            float4 u = *(const float4*)&xa[(size_t)row * RANKL];
            float4 v = *(const float4*)&xa[(size_t)row * RANKL + 4];
            la[r][0] = u.x; la[r][1] = u.y; la[r][2] = u.z; la[r][3] = u.w;
            la[r][4] = v.x; la[r][5] = v.y; la[r][6] = v.z; la[r][7] = v.w;
        }
#pragma unroll
        for (int nt = 0; nt < 4; nt++) {
#pragma unroll
            for (int r = 0; r < 4; r++) {
                float s = 0.f;
#pragma unroll
                for (int k = 0; k < RANKL; k++) s += la[r][k] * lb[nt][k];
                float val = acc[mt][nt][r] + LORA_SCALE * s;
                size_t row = bm + wm * 128 + mt * 16 + quad * 4 + r;
                size_t col = bn + wn * 64 + nt * 16 + c;
                Cout[row * N + col] = f2bf(val);
            }
        }
    }
}

// Output projection (fp32 out) -- m97-structure core (known-good)
__global__ __launch_bounds__(256) void gemm_wo(
    const ushort_t* __restrict__ A, const ushort_t* __restrict__ Wob,
    float* __restrict__ out, const float* __restrict__ xa_o,
    const float* __restrict__ oB)
{
    __shared__ ushort_t As[128 * 32];
    __shared__ ushort_t Bs[128 * 32];
    gemm_core(A, Wob, out, HIDDEN, NQ * HD, blockIdx.x * 128, blockIdx.y * 128,
              xa_o, oB, LORA_SCALE, 0, As, Bs);
}

// ---------------------------------------------------------------------------
// RoPE for Q and K in one kernel.
// ---------------------------------------------------------------------------
__global__ __launch_bounds__(256) void rope_qk(
    const ushort_t* __restrict__ qlin, const ushort_t* __restrict__ klin,
    ushort_t* __restrict__ qb, ushort_t* __restrict__ kb)
{
    int bs = blockIdx.x;
    int s = bs & (SEQ - 1);
    int b = bs >> 11;
    int t = threadIdx.x;
    int p = t & 63;
    float inv = exp2f(-(float)p * 0.20762050593046f); // 10000^(-p/64)
    float ang = (float)s * inv;
    float cc = cosf(ang), si = sinf(ang);
#pragma unroll
    for (int j = 0; j < 6; j++) {
        int item = t + 256 * j;
        int hh = item >> 6;       // 0..23
        unsigned int pk;
        ushort_t* dst;
        if (hh < NQ) {
            pk = *(const unsigned int*)&qlin[(size_t)bs * (NQ * HD) + hh * HD + 2 * p];
            dst = qb + (((size_t)(b * NQ + hh) * SEQ) + s) * HD + 2 * p;
        } else {
            int kh = hh - NQ;
            pk = *(const unsigned int*)&klin[(size_t)bs * (NKV * HD) + kh * HD + 2 * p];
            dst = kb + (((size_t)(b * NKV + kh) * SEQ) + s) * HD + 2 * p;
        }
        float xr = bf2f((ushort_t)(pk & 0xffff));
        float xi = bf2f((ushort_t)(pk >> 16));
        float rr = xr * cc - xi * si;
        float ri = xr * si + xi * cc;
        *(unsigned int*)dst = ((unsigned int)f2bf(ri) << 16) | f2bf(rr);
    }
}

// ---------------------------------------------------------------------------
// V transpose: v_lin [b*S][kvh*128+d] -> Vt [b][kvh][d][s]
// ---------------------------------------------------------------------------
__global__ __launch_bounds__(256) void v_transpose(
    const ushort_t* __restrict__ vlin, ushort_t* __restrict__ Vt)
{
    int bk = blockIdx.x;
    int b = bk >> 3, kvh = bk & 7;
    int s0 = blockIdx.y * 64, d0 = blockIdx.z * 64;
    __shared__ ushort_t tile[64 * 72];
    int t = threadIdx.x;
#pragma unroll
    for (int i = 0; i < 2; i++) {
        int id = t + 256 * i;
        int r = id >> 3, cc = id & 7;
        uint4 v = *(const uint4*)&vlin[(size_t)(b * SEQ + s0 + r) * (NKV * HD)
                                       + kvh * HD + d0 + cc * 8];
        *(uint4*)&tile[r * 72 + cc * 8] = v;
    }
    __syncthreads();
#pragma unroll
    for (int i = 0; i < 2; i++) {
        int id = t + 256 * i;
        int dr = id >> 3, sc = id & 7;
        ushort_t tmp[8];
#pragma unroll
        for (int e = 0; e < 8; e++) tmp[e] = tile[(sc * 8 + e) * 72 + dr];
        *(uint4*)&Vt[((size_t)(b * NKV + kvh) * HD + d0 + dr) * SEQ + s0 + sc * 8]
            = *(uint4*)tmp;
    }
}

// ---------------------------------------------------------------------------
// MFMA flash attention v4: 128-row q-tiles, 32 q-rows per wave.
// Each K/V fragment read from LDS feeds TWO MFMAs (one per 16-row q-block)
// -> LDS read bytes per FLOP halved vs v3. Block = 4 waves; q-tile pairs
// (a, 15-a) -> uniform 34 key-tiles/block. Constant-max softmax.
// Ping-pong K/V staging, ONE barrier per tile.
// Q,K: [b][h][s][128]; V: [b][kvh][d][s]; O: bf16 [b*s][h*128+d].
// ---------------------------------------------------------------------------
__global__ __launch_bounds__(256, 2) void attn_mfma4(
    const ushort_t* __restrict__ Q, const ushort_t* __restrict__ K,
    const ushort_t* __restrict__ V, ushort_t* __restrict__ O)
{
    __shared__ ushort_t Ks[2][64 * 128];    // 16 KB x2
    __shared__ ushort_t Vs[2][128 * 64];    // 16 KB x2
    __shared__ ushort_t Psh[4][16 * 68];    // 8.5 KB (reused per q-block)

    const int t = threadIdx.x;
    const int lane = t & 63;
    const int w = t >> 6;
    const int quad = lane >> 4;
    const int c = lane & 15;
    const int q4 = quad * 4;
    const int c7 = c & 7;

    const int head = blockIdx.x >> 3;     // b*NQ + h  (0..31)
    const int a = blockIdx.x & 7;         // pair index (0..7)
    const int h = head & (NQ - 1);
    const int b = head >> 4;
    const int kvh = b * NKV + (h >> 1);

    const ushort_t* Kg = K + (size_t)kvh * SEQ * HD;
    const ushort_t* Vg = V + (size_t)kvh * HD * SEQ;

    // staging address precompute (chunk id = t + 256*i)
    const ushort_t* gK[4]; const ushort_t* gV[4];
    int lo[4];
#pragma unroll
    for (int i = 0; i < 4; i++) {
        int cid = t + 256 * i;
        int kr = cid >> 4, kc = cid & 15;
        gK[i] = Kg + (size_t)kr * HD + ((kc ^ (kr & 7)) * 8);
        int vd = cid >> 3, vc = cid & 7;
        gV[i] = Vg + (size_t)vd * SEQ + ((vc ^ (vd & 7)) * 8);
        lo[i] = (i * 256 + (t & ~63)) * 8;
    }

#pragma unroll 1
    for (int half = 0; half < 2; half++) {
        const int qt = half ? (15 - a) : a;   // 128-row q-tile index
        const int Q0 = qt * 128;
        const int R0w = Q0 + w * 32;          // wave's first q-row (32 rows)

        // Q fragments (A-operand) for both 16-row q-blocks
        bf16x8 qf[2][4];
#pragma unroll
        for (int qb = 0; qb < 2; qb++) {
            const ushort_t* Qg = Q + ((size_t)head * SEQ + R0w + qb * 16 + c) * HD;
#pragma unroll
            for (int ch = 0; ch < 4; ch++)
                qf[qb][ch] = *(const bf16x8*)(Qg + ch * 32 + quad * 8);
        }

        f32x4 o[2][8];
#pragma unroll
        for (int qb = 0; qb < 2; qb++)
#pragma unroll
            for (int i = 0; i < 8; i++) o[qb][i] = (f32x4){0.f, 0.f, 0.f, 0.f};
        float lp[2][4] = {{0.f, 0.f, 0.f, 0.f}, {0.f, 0.f, 0.f, 0.f}};

        const int ntiles = 2 * qt + 2;

        // prime tile 0 into buffer 0
#pragma unroll
        for (int i = 0; i < 4; i++) gload_lds16(gK[i], &Ks[0][lo[i]]);
#pragma unroll
        for (int i = 0; i < 4; i++) gload_lds16(gV[i], &Vs[0][lo[i]]);
        __syncthreads();

        for (int tile = 0; tile < ntiles; ++tile) {
            const int cur = tile & 1;
            if (tile + 1 < ntiles) {
                const int j1 = (tile + 1) * 64;
#pragma unroll
                for (int i = 0; i < 4; i++)
                    gload_lds16(gK[i] + (size_t)j1 * HD, &Ks[cur ^ 1][lo[i]]);
#pragma unroll
                for (int i = 0; i < 4; i++)
                    gload_lds16(gV[i] + j1, &Vs[cur ^ 1][lo[i]]);
            }

            // ---- QK^T: each kf feeds both q-blocks
            f32x4 s0[4], s1[4];
#pragma unroll
            for (int tt = 0; tt < 4; tt++) {
                s0[tt] = (f32x4){0.f, 0.f, 0.f, 0.f};
                s1[tt] = (f32x4){0.f, 0.f, 0.f, 0.f};
            }
#pragma unroll
            for (int tt = 0; tt < 4; tt++) {
                const int krow = tt * 16 + c;
#pragma unroll
                for (int ch = 0; ch < 4; ch++) {
                    bf16x8 kf = *(const bf16x8*)
                        &Ks[cur][krow * 128 + (((ch * 4 + quad) ^ c7) * 8)];
                    s0[tt] = __builtin_amdgcn_mfma_f32_16x16x32_bf16(
                        qf[0][ch], kf, s0[tt], 0, 0, 0);
                    s1[tt] = __builtin_amdgcn_mfma_f32_16x16x32_bf16(
                        qf[1][ch], kf, s1[tt], 0, 0, 0);
                }
            }

            // ---- constant-max softmax + P-transpose via LDS, per q-block
            const int j0 = tile * 64;
            bf16x8 pf[2][2];
#pragma unroll
            for (int qb = 0; qb < 2; qb++) {
                const int Rb = R0w + qb * 16;
                const bool gate = (j0 + 63 > Rb);    // any masking in this q-block?
#pragma unroll
                for (int r = 0; r < 4; r++) {
                    const int row_g = Rb + q4 + r;
#pragma unroll
                    for (int tt = 0; tt < 4; tt++) {
                        float sv = (qb == 0) ? s0[tt][r] : s1[tt][r];
                        float p = exp2f(sv * SM_SCALE);
                        if (gate && (j0 + tt * 16 + c > row_g)) p = 0.f;
                        Psh[w][(q4 + r) * 68 + tt * 16 + c] = f2bf(p);
                        lp[qb][r] += p;
                    }
                }
                // read back A-layout fragments (same wave; compiler orders LDS ops)
#pragma unroll
                for (int ch = 0; ch < 2; ch++) {
                    int base = c * 68 + ch * 32 + quad * 8;
                    uint2 aa = *(const uint2*)&Psh[w][base];
                    uint2 bb = *(const uint2*)&Psh[w][base + 4];
                    uint4 u; u.x = aa.x; u.y = aa.y; u.z = bb.x; u.w = bb.y;
                    pf[qb][ch] = __builtin_bit_cast(bf16x8, u);
                }
            }

            // ---- PV: each vf feeds both q-blocks
#pragma unroll
            for (int dt = 0; dt < 8; dt++) {
                const int vrow = dt * 16 + c;
#pragma unroll
                for (int ch = 0; ch < 2; ch++) {
                    bf16x8 vf = *(const bf16x8*)
                        &Vs[cur][vrow * 64 + (((ch * 4 + quad) ^ c7) * 8)];
                    o[0][dt] = __builtin_amdgcn_mfma_f32_16x16x32_bf16(
                        pf[0][ch], vf, o[0][dt], 0, 0, 0);
                    o[1][dt] = __builtin_amdgcn_mfma_f32_16x16x32_bf16(
                        pf[1][ch], vf, o[1][dt], 0, 0, 0);
                }
            }
            __syncthreads();   // next tile staged + everyone done with cur
        }

        // ---- epilogue: reduce l over the 16 c-lanes, normalize, store
#pragma unroll
        for (int qb = 0; qb < 2; qb++) {
            float inv[4];
#pragma unroll
            for (int r = 0; r < 4; r++) {
                float v = lp[qb][r];
                v += __shfl_xor(v, 1);
                v += __shfl_xor(v, 2);
                v += __shfl_xor(v, 4);
                v += __shfl_xor(v, 8);
                inv[r] = 1.f / v;
            }
            size_t base = ((size_t)b * SEQ + R0w + qb * 16 + q4) * (NQ * HD)
                          + h * HD + c;
#pragma unroll
            for (int r = 0; r < 4; r++)
#pragma unroll
                for (int dt = 0; dt < 8; dt++)
                    O[base + (size_t)r * (NQ * HD) + dt * 16] =
                        f2bf(o[qb][dt][r] * inv[r]);
        }
    }
}

// ---------------------------------------------------------------------------
// Launch
// ---------------------------------------------------------------------------
extern "C" void kernel_launch(void* const* d_in, const int* in_sizes, int n_in,
                              void* d_out, int out_size, void* d_ws, size_t ws_size,
                              hipStream_t stream)
{
    const float* x  = (const float*)d_in[0];
    const float* Wq = (const float*)d_in[1];
    const float* Wk = (const float*)d_in[2];
    const float* Wv = (const float*)d_in[3];
    const float* Wo = (const float*)d_in[4];
    const float* qA = (const float*)d_in[5];
    const float* qB = (const float*)d_in[6];
    const float* kA = (const float*)d_in[7];
    const float* kB = (const float*)d_in[8];
    const float* vA = (const float*)d_in[9];
    const float* vB = (const float*)d_in[10];
    const float* oA = (const float*)d_in[11];
    const float* oB = (const float*)d_in[12];
    float* out = (float*)d_out;
    float* ws = (float*)d_ws;

    const int M = BATCH * SEQ;           // 4096

    float* xa_q = ws;
    float* xa_k = ws + 32768;
    float* xa_v = ws + 65536;
    float* xa_o = ws + 98304;
    ushort_t* q_lin = (ushort_t*)(ws + 131072);    // bf16 4096x2048
    ushort_t* k_lin = (ushort_t*)(ws + 4325376);   // bf16 4096x1024
    ushort_t* v_lin = (ushort_t*)(ws + 6422528);   // bf16 4096x1024
    ushort_t* qb    = (ushort_t*)(ws + 8519680);   // bf16 [B][16][S][128]
    ushort_t* kb    = (ushort_t*)(ws + 12713984);  // bf16 [B][8][S][128]
    ushort_t* vtb   = (ushort_t*)(ws + 14811136);  // bf16 [B][8][128][S]
    ushort_t* xbf   = (ushort_t*)(ws + 16908288);  // bf16 4096x2048
    ushort_t* Wqb   = (ushort_t*)(ws + 21102592);
    ushort_t* Wkb   = (ushort_t*)(ws + 23199744);
    ushort_t* Wvb   = (ushort_t*)(ws + 24248320);
    ushort_t* Wob   = (ushort_t*)(ws + 25296896);
    ushort_t* attn_out = q_lin;          // q_lin consumed before attention

    // fused x cast + q/k/v LoRA-A
    lora_cast_x<<<M, 256, 0, stream>>>(x, xbf, qA, kA, vA, xa_q, xa_k, xa_v);

    // all weight casts
    cast_weights<<<6144, 256, 0, stream>>>(Wq, Wk, Wv, Wo, Wqb, Wkb, Wvb, Wob);

    // fused QKV projection: 256^2 tiles, deep pipeline, fused LoRA
    gemm_qkv256<<<dim3(M / 256, 16), 512, 0, stream>>>(
        xbf, Wqb, Wkb, Wvb, q_lin, k_lin, v_lin,
        xa_q, xa_k, xa_v, qB, kB, vB);

    // RoPE relayout q,k; transpose v
    rope_qk<<<M, 256, 0, stream>>>(q_lin, k_lin, qb, kb);
    v_transpose<<<dim3(BATCH * NKV, SEQ / 64, HD / 64), 256, 0, stream>>>(v_lin, vtb);

    // flash attention v4 (128-row q-tiles, uniform 34-tile blocks)
    attn_mfma4<<<256, 256, 0, stream>>>(qb, kb, vtb, attn_out);

    // output projection with fused o-LoRA
    lora_xa_bf16<<<M, 256, 0, stream>>>(attn_out, oA, xa_o, NQ * HD);
    gemm_wo<<<dim3(M / 128, HIDDEN / 128), 256, 0, stream>>>(
        attn_out, Wob, out, xa_o, oB);
}

// Round 3
// 409.767 us; speedup vs baseline: 1.0612x; 1.0612x over previous
//
#include <hip/hip_runtime.h>
#include <hip/hip_bf16.h>
#include <cmath>

// Problem constants
#define HIDDEN 2048
#define SEQ 2048
#define BATCH 2
#define NQ 16
#define NKV 8
#define HD 128
#define RANKL 8
#define LORA_SCALE 2.0f
#define INV_SQRT_D 0.08838834764831845f
#define LOG2E 1.4426950408889634f
#define SM_SCALE (INV_SQRT_D * LOG2E)

typedef unsigned short ushort_t;
typedef __bf16 bf16x8 __attribute__((ext_vector_type(8)));
typedef float f32x4 __attribute__((ext_vector_type(4)));

static __device__ __forceinline__ ushort_t f2bf(float f) {
    __hip_bfloat16 h = __float2bfloat16(f);
    return *(ushort_t*)&h;
}
static __device__ __forceinline__ float bf2f(ushort_t u) {
    unsigned int v = ((unsigned int)u) << 16;
    return __builtin_bit_cast(float, v);
}
static __device__ __forceinline__ void gload_lds16(const ushort_t* g, ushort_t* l) {
    __builtin_amdgcn_global_load_lds(
        (const __attribute__((address_space(1))) unsigned int*)g,
        (__attribute__((address_space(3))) unsigned int*)l, 16, 0, 0);
}

// ---------------------------------------------------------------------------
// Fused: cast x row to bf16 + LoRA A-projections for q,k,v. One block/row.
// ---------------------------------------------------------------------------
__global__ __launch_bounds__(256) void lora_cast_x(
    const float* __restrict__ X, ushort_t* __restrict__ Xbf,
    const float* __restrict__ qA, const float* __restrict__ kA,
    const float* __restrict__ vA,
    float* __restrict__ oq, float* __restrict__ ok, float* __restrict__ ov)
{
    int m = blockIdx.x;
    int t = threadIdx.x;
    int c0 = t * 8;
    const float* xr = X + (size_t)m * HIDDEN + c0;
    float4 a = *(const float4*)xr;
    float4 b = *(const float4*)(xr + 4);
    float xv[8] = {a.x, a.y, a.z, a.w, b.x, b.y, b.z, b.w};
    uint4 o;
    o.x = (unsigned int)f2bf(xv[0]) | ((unsigned int)f2bf(xv[1]) << 16);
    o.y = (unsigned int)f2bf(xv[2]) | ((unsigned int)f2bf(xv[3]) << 16);
    o.z = (unsigned int)f2bf(xv[4]) | ((unsigned int)f2bf(xv[5]) << 16);
    o.w = (unsigned int)f2bf(xv[6]) | ((unsigned int)f2bf(xv[7]) << 16);
    *(uint4*)(Xbf + (size_t)m * HIDDEN + c0) = o;

    float p[3][RANKL];
#pragma unroll
    for (int w = 0; w < 3; w++)
#pragma unroll
        for (int r = 0; r < RANKL; r++) p[w][r] = 0.f;
    const float* Aw[3] = {qA, kA, vA};
#pragma unroll
    for (int e = 0; e < 8; e++) {
        float x8 = xv[e];
#pragma unroll
        for (int w = 0; w < 3; w++)
#pragma unroll
            for (int r = 0; r < RANKL; r++)
                p[w][r] += x8 * Aw[w][r * HIDDEN + c0 + e];
    }
#pragma unroll
    for (int w = 0; w < 3; w++)
#pragma unroll
        for (int r = 0; r < RANKL; r++) {
            float v = p[w][r];
            v += __shfl_xor(v, 32); v += __shfl_xor(v, 16);
            v += __shfl_xor(v, 8);  v += __shfl_xor(v, 4);
            v += __shfl_xor(v, 2);  v += __shfl_xor(v, 1);
            p[w][r] = v;
        }
    __shared__ float wred[4][3][RANKL];
    int wave = t >> 6, lane = t & 63;
    if (lane == 0) {
#pragma unroll
        for (int w = 0; w < 3; w++)
#pragma unroll
            for (int r = 0; r < RANKL; r++) wred[wave][w][r] = p[w][r];
    }
    __syncthreads();
    if (t < 3 * RANKL) {
        int w = t / RANKL, r = t % RANKL;
        float s = wred[0][w][r] + wred[1][w][r] + wred[2][w][r] + wred[3][w][r];
        float* dst = (w == 0) ? oq : (w == 1) ? ok : ov;
        dst[(size_t)m * RANKL + r] = s;
    }
}

// bf16-input LoRA A-projection (for o)
__global__ __launch_bounds__(256) void lora_xa_bf16(
    const ushort_t* __restrict__ X, const float* __restrict__ Aw,
    float* __restrict__ out, int K)
{
    int m = blockIdx.x;
    int t = threadIdx.x;
    const ushort_t* xr = X + (size_t)m * K;
    float p[RANKL];
#pragma unroll
    for (int r = 0; r < RANKL; r++) p[r] = 0.f;
    for (int c = t; c < K; c += 256) {
        float xv = bf2f(xr[c]);
#pragma unroll
        for (int r = 0; r < RANKL; r++) p[r] += xv * Aw[r * K + c];
    }
#pragma unroll
    for (int r = 0; r < RANKL; r++) {
        float v = p[r];
        v += __shfl_xor(v, 32); v += __shfl_xor(v, 16);
        v += __shfl_xor(v, 8);  v += __shfl_xor(v, 4);
        v += __shfl_xor(v, 2);  v += __shfl_xor(v, 1);
        p[r] = v;
    }
    __shared__ float wred[4][RANKL];
    int wave = t >> 6, lane = t & 63;
    if (lane == 0) {
#pragma unroll
        for (int r = 0; r < RANKL; r++) wred[wave][r] = p[r];
    }
    __syncthreads();
    if (t < RANKL) {
        out[(size_t)m * RANKL + t] =
            wred[0][t] + wred[1][t] + wred[2][t] + wred[3][t];
    }
}

// ---------------------------------------------------------------------------
// All four weight casts in one kernel. Chunks of 8 elements.
// ---------------------------------------------------------------------------
__global__ __launch_bounds__(256) void cast_weights(
    const float* __restrict__ Wq, const float* __restrict__ Wk,
    const float* __restrict__ Wv, const float* __restrict__ Wo,
    ushort_t* __restrict__ Wqb, ushort_t* __restrict__ Wkb,
    ushort_t* __restrict__ Wvb, ushort_t* __restrict__ Wob)
{
    size_t i = (size_t)blockIdx.x * 256 + threadIdx.x;   // 0..1572863
    const float* src; ushort_t* dst; size_t j;
    if (i < 524288)       { src = Wq; dst = Wqb; j = i; }
    else if (i < 786432)  { src = Wk; dst = Wkb; j = i - 524288; }
    else if (i < 1048576) { src = Wv; dst = Wvb; j = i - 786432; }
    else                  { src = Wo; dst = Wob; j = i - 1048576; }
    const float4* p = (const float4*)src + j * 2;
    float4 a = p[0], b = p[1];
    uint4 o;
    o.x = (unsigned int)f2bf(a.x) | ((unsigned int)f2bf(a.y) << 16);
    o.y = (unsigned int)f2bf(a.z) | ((unsigned int)f2bf(a.w) << 16);
    o.z = (unsigned int)f2bf(b.x) | ((unsigned int)f2bf(b.y) << 16);
    o.w = (unsigned int)f2bf(b.z) | ((unsigned int)f2bf(b.w) << 16);
    *(uint4*)(dst + j * 8) = o;
}

// ---------------------------------------------------------------------------
// bf16 MFMA GEMM core (m97 structure, 128x128 tile) -- kept for gemm_wo.
// ---------------------------------------------------------------------------
static __device__ __forceinline__ void gemm_core(
    const ushort_t* __restrict__ A, const ushort_t* __restrict__ B,
    void* __restrict__ Cout, int N, int K, int bm, int bn,
    const float* __restrict__ xa, const float* __restrict__ LB,
    float lscale, int out_bf16, ushort_t* As, ushort_t* Bs)
{
    const int t = threadIdx.x;
    const int lane = t & 63;
    const int w = t >> 6;
    const int quad = lane >> 4;
    const int c = lane & 15;

    const int wm = (w & 1) * 64;
    const int wn = (w >> 1) * 64;

    f32x4 acc[4][4];
#pragma unroll
    for (int i = 0; i < 4; i++)
#pragma unroll
        for (int j = 0; j < 4; j++) acc[i][j] = (f32x4){0.f, 0.f, 0.f, 0.f};

    const int p0 = w * 64 + lane;
    const int p1 = 256 + w * 64 + lane;
    const int r0 = p0 >> 2, g0 = (p0 & 3) ^ ((p0 >> 3) & 3);
    const int r1 = p1 >> 2, g1 = (p1 & 3) ^ ((p1 >> 3) & 3);
    const ushort_t* gA0 = A + (size_t)(bm + r0) * K + g0 * 8;
    const ushort_t* gA1 = A + (size_t)(bm + r1) * K + g1 * 8;
    const ushort_t* gB0 = B + (size_t)(bn + r0) * K + g0 * 8;
    const ushort_t* gB1 = B + (size_t)(bn + r1) * K + g1 * 8;
    ushort_t* lA0 = As + (size_t)(w * 64) * 8;
    ushort_t* lA1 = As + (size_t)(256 + w * 64) * 8;
    ushort_t* lB0 = Bs + (size_t)(w * 64) * 8;
    ushort_t* lB1 = Bs + (size_t)(256 + w * 64) * 8;

    const int csw = quad ^ ((c >> 1) & 3);

    for (int k0 = 0; k0 < K; k0 += 32) {
        __syncthreads();
        gload_lds16(gA0 + k0, lA0);
        gload_lds16(gA1 + k0, lA1);
        gload_lds16(gB0 + k0, lB0);
        gload_lds16(gB1 + k0, lB1);
        __syncthreads();

        bf16x8 af[4], bfr[4];
#pragma unroll
        for (int mt = 0; mt < 4; mt++)
            af[mt] = *(const bf16x8*)&As[((wm + mt * 16 + c) * 4 + csw) * 8];
#pragma unroll
        for (int nt = 0; nt < 4; nt++)
            bfr[nt] = *(const bf16x8*)&Bs[((wn + nt * 16 + c) * 4 + csw) * 8];
#pragma unroll
        for (int mt = 0; mt < 4; mt++)
#pragma unroll
            for (int nt = 0; nt < 4; nt++)
                acc[mt][nt] = __builtin_amdgcn_mfma_f32_16x16x32_bf16(
                    af[mt], bfr[nt], acc[mt][nt], 0, 0, 0);
    }

    float lb[4][RANKL];
#pragma unroll
    for (int nt = 0; nt < 4; nt++) {
        int col = bn + wn + nt * 16 + c;
        float4 u = *(const float4*)&LB[(size_t)col * RANKL];
        float4 v = *(const float4*)&LB[(size_t)col * RANKL + 4];
        lb[nt][0] = u.x; lb[nt][1] = u.y; lb[nt][2] = u.z; lb[nt][3] = u.w;
        lb[nt][4] = v.x; lb[nt][5] = v.y; lb[nt][6] = v.z; lb[nt][7] = v.w;
    }
#pragma unroll
    for (int mt = 0; mt < 4; mt++) {
        float la[4][RANKL];
#pragma unroll
        for (int r = 0; r < 4; r++) {
            int row = bm + wm + mt * 16 + quad * 4 + r;
            float4 u = *(const float4*)&xa[(size_t)row * RANKL];
            float4 v = *(const float4*)&xa[(size_t)row * RANKL + 4];
            la[r][0] = u.x; la[r][1] = u.y; la[r][2] = u.z; la[r][3] = u.w;
            la[r][4] = v.x; la[r][5] = v.y; la[r][6] = v.z; la[r][7] = v.w;
        }
#pragma unroll
        for (int nt = 0; nt < 4; nt++) {
#pragma unroll
            for (int r = 0; r < 4; r++) {
                float s = 0.f;
#pragma unroll
                for (int k = 0; k < RANKL; k++) s += la[r][k] * lb[nt][k];
                float val = acc[mt][nt][r] + lscale * s;
                size_t row = bm + wm + mt * 16 + quad * 4 + r;
                size_t col = bn + wn + nt * 16 + c;
                if (out_bf16)
                    ((ushort_t*)Cout)[row * N + col] = f2bf(val);
                else
                    ((float*)Cout)[row * N + col] = val;
            }
        }
    }
}

// ---------------------------------------------------------------------------
// 256x256-tile 8-wave deep-pipelined QKV GEMM (T2+T3+T4+T5).
// ---------------------------------------------------------------------------
#define BKT 64
#define NKT (HIDDEN / BKT)   // 32

__global__ __launch_bounds__(512, 2) void gemm_qkv256(
    const ushort_t* __restrict__ A,
    const ushort_t* __restrict__ Wqb, const ushort_t* __restrict__ Wkb,
    const ushort_t* __restrict__ Wvb,
    ushort_t* __restrict__ q_lin, ushort_t* __restrict__ k_lin,
    ushort_t* __restrict__ v_lin,
    const float* __restrict__ xa_q, const float* __restrict__ xa_k,
    const float* __restrict__ xa_v,
    const float* __restrict__ qB, const float* __restrict__ kB,
    const float* __restrict__ vB)
{
    __shared__ __align__(16) ushort_t As[2][256 * BKT];   // 64 KiB
    __shared__ __align__(16) ushort_t Bs[2][256 * BKT];   // 64 KiB

    const int t = threadIdx.x;
    const int lane = t & 63;
    const int w = t >> 6;          // 0..7
    const int wm = w >> 2;         // 0..1  (M half)
    const int wn = w & 3;          // 0..3  (N quarter)
    const int quad = lane >> 4;
    const int c = lane & 15;
    const int c7 = c & 7;

    const int bc = blockIdx.y;
    const ushort_t* Bmat; ushort_t* Cout; const float* xa; const float* LB;
    int N, bn;
    if (bc < 8)       { Bmat = Wqb; Cout = q_lin; xa = xa_q; LB = qB; N = 2048; bn = bc * 256; }
    else if (bc < 12) { Bmat = Wkb; Cout = k_lin; xa = xa_k; LB = kB; N = 1024; bn = (bc - 8) * 256; }
    else              { Bmat = Wvb; Cout = v_lin; xa = xa_v; LB = vB; N = 1024; bn = (bc - 12) * 256; }
    const int bm = blockIdx.x * 256;

    // ---- staging addressing (chunk-XOR involution, linear LDS dest)
    const int r8  = lane >> 3;           // 0..7 row within 8-row group
    const int ksl = (lane & 7) ^ r8;     // swizzled k-chunk for this lane
    const int ga  = wn;                  // index within A staging group (wm)
    const int bh  = wn >> 1;             // B half this wave consumes
    const int gb  = wm * 2 + (wn & 1);   // index within B staging group (bh)

    const ushort_t* gAb = A    + (size_t)(bm + wm * 128 + ga * 8 + r8) * HIDDEN + ksl * 8;
    const ushort_t* gBb = Bmat + (size_t)(bn + bh * 128 + gb * 8 + r8) * HIDDEN + ksl * 8;
    const int lAoff = (wm * 128 + ga * 8) * BKT;   // + j*32*BKT
    const int lBoff = (bh * 128 + gb * 8) * BKT;

    // ---- prologue: tile 0 fully, tile 1 parts j=0..2
#pragma unroll
    for (int j = 0; j < 4; j++) {
        gload_lds16(gAb + (size_t)j * 32 * HIDDEN, &As[0][lAoff + j * 32 * BKT]);
        gload_lds16(gBb + (size_t)j * 32 * HIDDEN, &Bs[0][lBoff + j * 32 * BKT]);
    }
#pragma unroll
    for (int j = 0; j < 3; j++) {
        gload_lds16(gAb + (size_t)j * 32 * HIDDEN + BKT, &As[1][lAoff + j * 32 * BKT]);
        gload_lds16(gBb + (size_t)j * 32 * HIDDEN + BKT, &Bs[1][lBoff + j * 32 * BKT]);
    }

    f32x4 acc[8][4];
#pragma unroll
    for (int i = 0; i < 8; i++)
#pragma unroll
        for (int j = 0; j < 4; j++) acc[i][j] = (f32x4){0.f, 0.f, 0.f, 0.f};

#pragma unroll 1
    for (int T = 0; T < NKT; ++T) {
        const int cur = T & 1;
        const ushort_t* cA = As[cur];
        const ushort_t* cB = Bs[cur];
        bf16x8 bfr[4][2];

#pragma unroll
        for (int q = 0; q < 4; ++q) {
            if (q == 0) {
                asm volatile("s_waitcnt vmcnt(6)" ::: "memory");
            }
            __builtin_amdgcn_sched_barrier(0);
            __builtin_amdgcn_s_barrier();
            __builtin_amdgcn_sched_barrier(0);

            // ---- ds reads: A quadrant q (4 x b128); B all (8 x b128) at q==0
            bf16x8 af[2][2];
#pragma unroll
            for (int m2 = 0; m2 < 2; ++m2) {
                const int row = wm * 128 + (q * 2 + m2) * 16 + c;
#pragma unroll
                for (int kh = 0; kh < 2; ++kh)
                    af[m2][kh] = *(const bf16x8*)
                        &cA[row * BKT + (((kh * 4 + quad) ^ c7) * 8)];
            }
            if (q == 0) {
#pragma unroll
                for (int nt = 0; nt < 4; ++nt) {
                    const int rowb = wn * 64 + nt * 16 + c;
#pragma unroll
                    for (int kh = 0; kh < 2; ++kh)
                        bfr[nt][kh] = *(const bf16x8*)
                            &cB[rowb * BKT + (((kh * 4 + quad) ^ c7) * 8)];
                }
            }

            // ---- staging
            if (q == 0) {
                const int tl = T + 1;
                if (tl < NKT) {
                    gload_lds16(gAb + (size_t)3 * 32 * HIDDEN + (size_t)tl * BKT,
                                &As[cur ^ 1][lAoff + 3 * 32 * BKT]);
                    gload_lds16(gBb + (size_t)3 * 32 * HIDDEN + (size_t)tl * BKT,
                                &Bs[cur ^ 1][lBoff + 3 * 32 * BKT]);
                }
            } else {
                const int tl = T + 2;
                if (tl < NKT) {
                    const int j = q - 1;
                    gload_lds16(gAb + (size_t)j * 32 * HIDDEN + (size_t)tl * BKT,
                                &As[cur][lAoff + j * 32 * BKT]);
                    gload_lds16(gBb + (size_t)j * 32 * HIDDEN + (size_t)tl * BKT,
                                &Bs[cur][lBoff + j * 32 * BKT]);
                }
            }

            // ---- 16 MFMA: C-quadrant (32 rows x 64 cols) over K=64
            __builtin_amdgcn_s_setprio(1);
#pragma unroll
            for (int m2 = 0; m2 < 2; ++m2)
#pragma unroll
                for (int nt = 0; nt < 4; ++nt)
#pragma unroll
                    for (int kh = 0; kh < 2; ++kh)
                        acc[q * 2 + m2][nt] = __builtin_amdgcn_mfma_f32_16x16x32_bf16(
                            af[m2][kh], bfr[nt][kh], acc[q * 2 + m2][nt], 0, 0, 0);
            __builtin_amdgcn_s_setprio(0);
        }
    }

    // ---- epilogue: fused LoRA rank-8 + bf16 store
    float lb[4][RANKL];
#pragma unroll
    for (int nt = 0; nt < 4; nt++) {
        int col = bn + wn * 64 + nt * 16 + c;
        float4 u = *(const float4*)&LB[(size_t)col * RANKL];
        float4 v = *(const float4*)&LB[(size_t)col * RANKL + 4];
        lb[nt][0] = u.x; lb[nt][1] = u.y; lb[nt][2] = u.z; lb[nt][3] = u.w;
        lb[nt][4] = v.x; lb[nt][5] = v.y; lb[nt][6] = v.z; lb[nt][7] = v.w;
    }
#pragma unroll
    for (int mt = 0; mt < 8; mt++) {
        float la[4][RANKL];
#pragma unroll
        for (int r = 0; r < 4; r++) {
            int row = bm + wm * 128 + mt * 16 + quad * 4 + r;
            float4 u = *(const float4*)&xa[(size_t)row * RANKL];
            float4 v = *(const float4*)&xa[(size_t)row * RANKL + 4];
            la[r][0] = u.x; la[r][1] = u.y; la[r][2] = u.z; la[r][3] = u.w;
            la[r][4] = v.x; la[r][5] = v.y; la[r][6] = v.z; la[r][7] = v.w;
        }
#pragma unroll
        for (int nt = 0; nt < 4; nt++) {
#pragma unroll
            for (int r = 0; r < 4; r++) {
                float s = 0.f;
#pragma unroll
                for (int k = 0; k < RANKL; k++) s += la[r][k] * lb[nt][k];
                float val = acc[mt][nt][r] + LORA_SCALE * s;
                size_t row = bm + wm * 128 + mt * 16 + quad * 4 + r;
                size_t col = bn + wn * 64 + nt * 16 + c;
                Cout[row * N + col] = f2bf(val);
            }
        }
    }
}

// Output projection (fp32 out) -- m97-structure core (known-good)
__global__ __launch_bounds__(256) void gemm_wo(
    const ushort_t* __restrict__ A, const ushort_t* __restrict__ Wob,
    float* __restrict__ out, const float* __restrict__ xa_o,
    const float* __restrict__ oB)
{
    __shared__ ushort_t As[128 * 32];
    __shared__ ushort_t Bs[128 * 32];
    gemm_core(A, Wob, out, HIDDEN, NQ * HD, blockIdx.x * 128, blockIdx.y * 128,
              xa_o, oB, LORA_SCALE, 0, As, Bs);
}

// ---------------------------------------------------------------------------
// RoPE for Q and K in one kernel.
// ---------------------------------------------------------------------------
__global__ __launch_bounds__(256) void rope_qk(
    const ushort_t* __restrict__ qlin, const ushort_t* __restrict__ klin,
    ushort_t* __restrict__ qb, ushort_t* __restrict__ kb)
{
    int bs = blockIdx.x;
    int s = bs & (SEQ - 1);
    int b = bs >> 11;
    int t = threadIdx.x;
    int p = t & 63;
    float inv = exp2f(-(float)p * 0.20762050593046f); // 10000^(-p/64)
    float ang = (float)s * inv;
    float cc = cosf(ang), si = sinf(ang);
#pragma unroll
    for (int j = 0; j < 6; j++) {
        int item = t + 256 * j;
        int hh = item >> 6;       // 0..23
        unsigned int pk;
        ushort_t* dst;
        if (hh < NQ) {
            pk = *(const unsigned int*)&qlin[(size_t)bs * (NQ * HD) + hh * HD + 2 * p];
            dst = qb + (((size_t)(b * NQ + hh) * SEQ) + s) * HD + 2 * p;
        } else {
            int kh = hh - NQ;
            pk = *(const unsigned int*)&klin[(size_t)bs * (NKV * HD) + kh * HD + 2 * p];
            dst = kb + (((size_t)(b * NKV + kh) * SEQ) + s) * HD + 2 * p;
        }
        float xr = bf2f((ushort_t)(pk & 0xffff));
        float xi = bf2f((ushort_t)(pk >> 16));
        float rr = xr * cc - xi * si;
        float ri = xr * si + xi * cc;
        *(unsigned int*)dst = ((unsigned int)f2bf(ri) << 16) | f2bf(rr);
    }
}

// ---------------------------------------------------------------------------
// V transpose: v_lin [b*S][kvh*128+d] -> Vt [b][kvh][d][s]
// ---------------------------------------------------------------------------
__global__ __launch_bounds__(256) void v_transpose(
    const ushort_t* __restrict__ vlin, ushort_t* __restrict__ Vt)
{
    int bk = blockIdx.x;
    int b = bk >> 3, kvh = bk & 7;
    int s0 = blockIdx.y * 64, d0 = blockIdx.z * 64;
    __shared__ ushort_t tile[64 * 72];
    int t = threadIdx.x;
#pragma unroll
    for (int i = 0; i < 2; i++) {
        int id = t + 256 * i;
        int r = id >> 3, cc = id & 7;
        uint4 v = *(const uint4*)&vlin[(size_t)(b * SEQ + s0 + r) * (NKV * HD)
                                       + kvh * HD + d0 + cc * 8];
        *(uint4*)&tile[r * 72 + cc * 8] = v;
    }
    __syncthreads();
#pragma unroll
    for (int i = 0; i < 2; i++) {
        int id = t + 256 * i;
        int dr = id >> 3, sc = id & 7;
        ushort_t tmp[8];
#pragma unroll
        for (int e = 0; e < 8; e++) tmp[e] = tile[(sc * 8 + e) * 72 + dr];
        *(uint4*)&Vt[((size_t)(b * NKV + kvh) * HD + d0 + dr) * SEQ + s0 + sc * 8]
            = *(uint4*)tmp;
    }
}

// ---------------------------------------------------------------------------
// MFMA flash attention v5: 128-row q-tiles, 32 q-rows per wave (each K/V
// LDS fragment feeds TWO MFMAs), ONE q-tile per block -> 512 blocks so each
// CU holds two INDEPENDENT blocks (no shared barrier -> real overlap).
// Complementary pairing: blocks i and i+256 have tile counts summing to 34,
// and with round-robin dispatch land on the same CU -> uniform load.
// Constant-max softmax; ping-pong K/V staging; ONE barrier per tile.
// Q,K: [b][h][s][128]; V: [b][kvh][d][s]; O: bf16 [b*s][h*128+d].
// ---------------------------------------------------------------------------
__global__ __launch_bounds__(256, 2) void attn_mfma5(
    const ushort_t* __restrict__ Q, const ushort_t* __restrict__ K,
    const ushort_t* __restrict__ V, ushort_t* __restrict__ O)
{
    __shared__ ushort_t Ks[2][64 * 128];    // 16 KB x2
    __shared__ ushort_t Vs[2][128 * 64];    // 16 KB x2
    __shared__ ushort_t Psh[4][16 * 68];    // 8.5 KB (reused per q-block)

    const int t = threadIdx.x;
    const int lane = t & 63;
    const int w = t >> 6;
    const int quad = lane >> 4;
    const int c = lane & 15;
    const int q4 = quad * 4;
    const int c7 = c & 7;

    const int idx = blockIdx.x & 255;     // (head, a)
    const int sel = blockIdx.x >> 8;      // 0: long half, 1: short half
    const int head = idx >> 3;            // b*NQ + h  (0..31)
    const int a = idx & 7;                // 0..7
    const int qt = sel ? a : (15 - a);    // 128-row q-tile index
    const int h = head & (NQ - 1);
    const int b = head >> 4;
    const int kvh = b * NKV + (h >> 1);

    const ushort_t* Kg = K + (size_t)kvh * SEQ * HD;
    const ushort_t* Vg = V + (size_t)kvh * HD * SEQ;

    // staging address precompute (chunk id = t + 256*i)
    const ushort_t* gK[4]; const ushort_t* gV[4];
    int lo[4];
#pragma unroll
    for (int i = 0; i < 4; i++) {
        int cid = t + 256 * i;
        int kr = cid >> 4, kc = cid & 15;
        gK[i] = Kg + (size_t)kr * HD + ((kc ^ (kr & 7)) * 8);
        int vd = cid >> 3, vc = cid & 7;
        gV[i] = Vg + (size_t)vd * SEQ + ((vc ^ (vd & 7)) * 8);
        lo[i] = (i * 256 + (t & ~63)) * 8;
    }

    const int R0w = qt * 128 + w * 32;        // wave's first q-row (32 rows)

    // Q fragments (A-operand) for both 16-row q-blocks
    bf16x8 qf[2][4];
#pragma unroll
    for (int qb = 0; qb < 2; qb++) {
        const ushort_t* Qg = Q + ((size_t)head * SEQ + R0w + qb * 16 + c) * HD;
#pragma unroll
        for (int ch = 0; ch < 4; ch++)
            qf[qb][ch] = *(const bf16x8*)(Qg + ch * 32 + quad * 8);
    }

    f32x4 o[2][8];
#pragma unroll
    for (int qb = 0; qb < 2; qb++)
#pragma unroll
        for (int i = 0; i < 8; i++) o[qb][i] = (f32x4){0.f, 0.f, 0.f, 0.f};
    float lp[2][4] = {{0.f, 0.f, 0.f, 0.f}, {0.f, 0.f, 0.f, 0.f}};

    const int ntiles = 2 * qt + 2;

    // prime tile 0 into buffer 0
#pragma unroll
    for (int i = 0; i < 4; i++) gload_lds16(gK[i], &Ks[0][lo[i]]);
#pragma unroll
    for (int i = 0; i < 4; i++) gload_lds16(gV[i], &Vs[0][lo[i]]);
    __syncthreads();

    for (int tile = 0; tile < ntiles; ++tile) {
        const int cur = tile & 1;
        if (tile + 1 < ntiles) {
            const int j1 = (tile + 1) * 64;
#pragma unroll
            for (int i = 0; i < 4; i++)
                gload_lds16(gK[i] + (size_t)j1 * HD, &Ks[cur ^ 1][lo[i]]);
#pragma unroll
            for (int i = 0; i < 4; i++)
                gload_lds16(gV[i] + j1, &Vs[cur ^ 1][lo[i]]);
        }

        // ---- QK^T: each kf feeds both q-blocks
        f32x4 s0[4], s1[4];
#pragma unroll
        for (int tt = 0; tt < 4; tt++) {
            s0[tt] = (f32x4){0.f, 0.f, 0.f, 0.f};
            s1[tt] = (f32x4){0.f, 0.f, 0.f, 0.f};
        }
#pragma unroll
        for (int tt = 0; tt < 4; tt++) {
            const int krow = tt * 16 + c;
#pragma unroll
            for (int ch = 0; ch < 4; ch++) {
                bf16x8 kf = *(const bf16x8*)
                    &Ks[cur][krow * 128 + (((ch * 4 + quad) ^ c7) * 8)];
                s0[tt] = __builtin_amdgcn_mfma_f32_16x16x32_bf16(
                    qf[0][ch], kf, s0[tt], 0, 0, 0);
                s1[tt] = __builtin_amdgcn_mfma_f32_16x16x32_bf16(
                    qf[1][ch], kf, s1[tt], 0, 0, 0);
            }
        }

        // ---- constant-max softmax + P-transpose via LDS, per q-block
        const int j0 = tile * 64;
        bf16x8 pf[2][2];
#pragma unroll
        for (int qb = 0; qb < 2; qb++) {
            const int Rb = R0w + qb * 16;
            const bool gate = (j0 + 63 > Rb);    // any masking in this q-block?
#pragma unroll
            for (int r = 0; r < 4; r++) {
                const int row_g = Rb + q4 + r;
#pragma unroll
                for (int tt = 0; tt < 4; tt++) {
                    float sv = (qb == 0) ? s0[tt][r] : s1[tt][r];
                    float p = exp2f(sv * SM_SCALE);
                    if (gate && (j0 + tt * 16 + c > row_g)) p = 0.f;
                    Psh[w][(q4 + r) * 68 + tt * 16 + c] = f2bf(p);
                    lp[qb][r] += p;
                }
            }
            // read back A-layout fragments (same wave; compiler orders LDS ops)
#pragma unroll
            for (int ch = 0; ch < 2; ch++) {
                int base = c * 68 + ch * 32 + quad * 8;
                uint2 aa = *(const uint2*)&Psh[w][base];
                uint2 bb = *(const uint2*)&Psh[w][base + 4];
                uint4 u; u.x = aa.x; u.y = aa.y; u.z = bb.x; u.w = bb.y;
                pf[qb][ch] = __builtin_bit_cast(bf16x8, u);
            }
        }

        // ---- PV: each vf feeds both q-blocks
#pragma unroll
        for (int dt = 0; dt < 8; dt++) {
            const int vrow = dt * 16 + c;
#pragma unroll
            for (int ch = 0; ch < 2; ch++) {
                bf16x8 vf = *(const bf16x8*)
                    &Vs[cur][vrow * 64 + (((ch * 4 + quad) ^ c7) * 8)];
                o[0][dt] = __builtin_amdgcn_mfma_f32_16x16x32_bf16(
                    pf[0][ch], vf, o[0][dt], 0, 0, 0);
                o[1][dt] = __builtin_amdgcn_mfma_f32_16x16x32_bf16(
                    pf[1][ch], vf, o[1][dt], 0, 0, 0);
            }
        }
        __syncthreads();   // next tile staged + everyone done with cur
    }

    // ---- epilogue: reduce l over the 16 c-lanes, normalize, store
#pragma unroll
    for (int qb = 0; qb < 2; qb++) {
        float inv[4];
#pragma unroll
        for (int r = 0; r < 4; r++) {
            float v = lp[qb][r];
            v += __shfl_xor(v, 1);
            v += __shfl_xor(v, 2);
            v += __shfl_xor(v, 4);
            v += __shfl_xor(v, 8);
            inv[r] = 1.f / v;
        }
        size_t base = ((size_t)b * SEQ + R0w + qb * 16 + q4) * (NQ * HD)
                      + h * HD + c;
#pragma unroll
        for (int r = 0; r < 4; r++)
#pragma unroll
            for (int dt = 0; dt < 8; dt++)
                O[base + (size_t)r * (NQ * HD) + dt * 16] =
                    f2bf(o[qb][dt][r] * inv[r]);
    }
}

// ---------------------------------------------------------------------------
// Launch
// ---------------------------------------------------------------------------
extern "C" void kernel_launch(void* const* d_in, const int* in_sizes, int n_in,
                              void* d_out, int out_size, void* d_ws, size_t ws_size,
                              hipStream_t stream)
{
    const float* x  = (const float*)d_in[0];
    const float* Wq = (const float*)d_in[1];
    const float* Wk = (const float*)d_in[2];
    const float* Wv = (const float*)d_in[3];
    const float* Wo = (const float*)d_in[4];
    const float* qA = (const float*)d_in[5];
    const float* qB = (const float*)d_in[6];
    const float* kA = (const float*)d_in[7];
    const float* kB = (const float*)d_in[8];
    const float* vA = (const float*)d_in[9];
    const float* vB = (const float*)d_in[10];
    const float* oA = (const float*)d_in[11];
    const float* oB = (const float*)d_in[12];
    float* out = (float*)d_out;
    float* ws = (float*)d_ws;

    const int M = BATCH * SEQ;           // 4096

    float* xa_q = ws;
    float* xa_k = ws + 32768;
    float* xa_v = ws + 65536;
    float* xa_o = ws + 98304;
    ushort_t* q_lin = (ushort_t*)(ws + 131072);    // bf16 4096x2048
    ushort_t* k_lin = (ushort_t*)(ws + 4325376);   // bf16 4096x1024
    ushort_t* v_lin = (ushort_t*)(ws + 6422528);   // bf16 4096x1024
    ushort_t* qb    = (ushort_t*)(ws + 8519680);   // bf16 [B][16][S][128]
    ushort_t* kb    = (ushort_t*)(ws + 12713984);  // bf16 [B][8][S][128]
    ushort_t* vtb   = (ushort_t*)(ws + 14811136);  // bf16 [B][8][128][S]
    ushort_t* xbf   = (ushort_t*)(ws + 16908288);  // bf16 4096x2048
    ushort_t* Wqb   = (ushort_t*)(ws + 21102592);
    ushort_t* Wkb   = (ushort_t*)(ws + 23199744);
    ushort_t* Wvb   = (ushort_t*)(ws + 24248320);
    ushort_t* Wob   = (ushort_t*)(ws + 25296896);
    ushort_t* attn_out = q_lin;          // q_lin consumed before attention

    // fused x cast + q/k/v LoRA-A
    lora_cast_x<<<M, 256, 0, stream>>>(x, xbf, qA, kA, vA, xa_q, xa_k, xa_v);

    // all weight casts
    cast_weights<<<6144, 256, 0, stream>>>(Wq, Wk, Wv, Wo, Wqb, Wkb, Wvb, Wob);

    // fused QKV projection: 256^2 tiles, deep pipeline, fused LoRA
    gemm_qkv256<<<dim3(M / 256, 16), 512, 0, stream>>>(
        xbf, Wqb, Wkb, Wvb, q_lin, k_lin, v_lin,
        xa_q, xa_k, xa_v, qB, kB, vB);

    // RoPE relayout q,k; transpose v
    rope_qk<<<M, 256, 0, stream>>>(q_lin, k_lin, qb, kb);
    v_transpose<<<dim3(BATCH * NKV, SEQ / 64, HD / 64), 256, 0, stream>>>(v_lin, vtb);

    // flash attention v5 (one 128-row q-tile per block; 512 blocks,
    // complementary pairing -> 2 independent blocks/CU, uniform 34 tiles/CU)
    attn_mfma5<<<512, 256, 0, stream>>>(qb, kb, vtb, attn_out);

    // output projection with fused o-LoRA
    lora_xa_bf16<<<M, 256, 0, stream>>>(attn_out, oA, xa_o, NQ * HD);
    gemm_wo<<<dim3(M / 128, HIDDEN / 128), 256, 0, stream>>>(
        attn_out, Wob, out, xa_o, oB);
}

// Round 4
// 389.202 us; speedup vs baseline: 1.1173x; 1.0528x over previous
//
#include <hip/hip_runtime.h>
#include <hip/hip_bf16.h>
#include <cmath>

// Problem constants
#define HIDDEN 2048
#define SEQ 2048
#define BATCH 2
#define NQ 16
#define NKV 8
#define HD 128
#define RANKL 8
#define LORA_SCALE 2.0f
#define INV_SQRT_D 0.08838834764831845f
#define LOG2E 1.4426950408889634f
#define SM_SCALE (INV_SQRT_D * LOG2E)

typedef unsigned short ushort_t;
typedef __bf16 bf16x8 __attribute__((ext_vector_type(8)));
typedef float f32x4 __attribute__((ext_vector_type(4)));

static __device__ __forceinline__ ushort_t f2bf(float f) {
    __hip_bfloat16 h = __float2bfloat16(f);
    return *(ushort_t*)&h;
}
static __device__ __forceinline__ float bf2f(ushort_t u) {
    unsigned int v = ((unsigned int)u) << 16;
    return __builtin_bit_cast(float, v);
}
static __device__ __forceinline__ void gload_lds16(const ushort_t* g, ushort_t* l) {
    __builtin_amdgcn_global_load_lds(
        (const __attribute__((address_space(1))) unsigned int*)g,
        (__attribute__((address_space(3))) unsigned int*)l, 16, 0, 0);
}

// ---------------------------------------------------------------------------
// Fused prologue: blocks [0,4096) = x cast + q/k/v LoRA-A projections;
// blocks [4096,10240) = all four weight casts. Independent work co-executes.
// ---------------------------------------------------------------------------
__global__ __launch_bounds__(256) void prep_fused(
    const float* __restrict__ X, ushort_t* __restrict__ Xbf,
    const float* __restrict__ qA, const float* __restrict__ kA,
    const float* __restrict__ vA,
    float* __restrict__ oq, float* __restrict__ ok, float* __restrict__ ov,
    const float* __restrict__ Wq, const float* __restrict__ Wk,
    const float* __restrict__ Wv, const float* __restrict__ Wo,
    ushort_t* __restrict__ Wqb, ushort_t* __restrict__ Wkb,
    ushort_t* __restrict__ Wvb, ushort_t* __restrict__ Wob)
{
    __shared__ float wred[4][3][RANKL];
    int t = threadIdx.x;
    if (blockIdx.x < 4096) {
        int m = blockIdx.x;
        int c0 = t * 8;
        const float* xr = X + (size_t)m * HIDDEN + c0;
        float4 a = *(const float4*)xr;
        float4 b = *(const float4*)(xr + 4);
        float xv[8] = {a.x, a.y, a.z, a.w, b.x, b.y, b.z, b.w};
        uint4 o;
        o.x = (unsigned int)f2bf(xv[0]) | ((unsigned int)f2bf(xv[1]) << 16);
        o.y = (unsigned int)f2bf(xv[2]) | ((unsigned int)f2bf(xv[3]) << 16);
        o.z = (unsigned int)f2bf(xv[4]) | ((unsigned int)f2bf(xv[5]) << 16);
        o.w = (unsigned int)f2bf(xv[6]) | ((unsigned int)f2bf(xv[7]) << 16);
        *(uint4*)(Xbf + (size_t)m * HIDDEN + c0) = o;

        float p[3][RANKL];
#pragma unroll
        for (int w = 0; w < 3; w++)
#pragma unroll
            for (int r = 0; r < RANKL; r++) p[w][r] = 0.f;
        const float* Aw[3] = {qA, kA, vA};
#pragma unroll
        for (int e = 0; e < 8; e++) {
            float x8 = xv[e];
#pragma unroll
            for (int w = 0; w < 3; w++)
#pragma unroll
                for (int r = 0; r < RANKL; r++)
                    p[w][r] += x8 * Aw[w][r * HIDDEN + c0 + e];
        }
#pragma unroll
        for (int w = 0; w < 3; w++)
#pragma unroll
            for (int r = 0; r < RANKL; r++) {
                float v = p[w][r];
                v += __shfl_xor(v, 32); v += __shfl_xor(v, 16);
                v += __shfl_xor(v, 8);  v += __shfl_xor(v, 4);
                v += __shfl_xor(v, 2);  v += __shfl_xor(v, 1);
                p[w][r] = v;
            }
        int wave = t >> 6, lane = t & 63;
        if (lane == 0) {
#pragma unroll
            for (int w = 0; w < 3; w++)
#pragma unroll
                for (int r = 0; r < RANKL; r++) wred[wave][w][r] = p[w][r];
        }
        __syncthreads();
        if (t < 3 * RANKL) {
            int w = t / RANKL, r = t % RANKL;
            float s = wred[0][w][r] + wred[1][w][r] + wred[2][w][r] + wred[3][w][r];
            float* dst = (w == 0) ? oq : (w == 1) ? ok : ov;
            dst[(size_t)m * RANKL + r] = s;
        }
    } else {
        size_t i = (size_t)(blockIdx.x - 4096) * 256 + t;   // 0..1572863
        const float* src; ushort_t* dst; size_t j;
        if (i < 524288)       { src = Wq; dst = Wqb; j = i; }
        else if (i < 786432)  { src = Wk; dst = Wkb; j = i - 524288; }
        else if (i < 1048576) { src = Wv; dst = Wvb; j = i - 786432; }
        else                  { src = Wo; dst = Wob; j = i - 1048576; }
        const float4* p = (const float4*)src + j * 2;
        float4 a = p[0], b = p[1];
        uint4 o;
        o.x = (unsigned int)f2bf(a.x) | ((unsigned int)f2bf(a.y) << 16);
        o.y = (unsigned int)f2bf(a.z) | ((unsigned int)f2bf(a.w) << 16);
        o.z = (unsigned int)f2bf(b.x) | ((unsigned int)f2bf(b.y) << 16);
        o.w = (unsigned int)f2bf(b.z) | ((unsigned int)f2bf(b.w) << 16);
        *(uint4*)(dst + j * 8) = o;
    }
}

// bf16-input LoRA A-projection (for o)
__global__ __launch_bounds__(256) void lora_xa_bf16(
    const ushort_t* __restrict__ X, const float* __restrict__ Aw,
    float* __restrict__ out, int K)
{
    int m = blockIdx.x;
    int t = threadIdx.x;
    const ushort_t* xr = X + (size_t)m * K;
    float p[RANKL];
#pragma unroll
    for (int r = 0; r < RANKL; r++) p[r] = 0.f;
    for (int c = t; c < K; c += 256) {
        float xv = bf2f(xr[c]);
#pragma unroll
        for (int r = 0; r < RANKL; r++) p[r] += xv * Aw[r * K + c];
    }
#pragma unroll
    for (int r = 0; r < RANKL; r++) {
        float v = p[r];
        v += __shfl_xor(v, 32); v += __shfl_xor(v, 16);
        v += __shfl_xor(v, 8);  v += __shfl_xor(v, 4);
        v += __shfl_xor(v, 2);  v += __shfl_xor(v, 1);
        p[r] = v;
    }
    __shared__ float wred[4][RANKL];
    int wave = t >> 6, lane = t & 63;
    if (lane == 0) {
#pragma unroll
        for (int r = 0; r < RANKL; r++) wred[wave][r] = p[r];
    }
    __syncthreads();
    if (t < RANKL) {
        out[(size_t)m * RANKL + t] =
            wred[0][t] + wred[1][t] + wred[2][t] + wred[3][t];
    }
}

// ---------------------------------------------------------------------------
// bf16 MFMA GEMM core (m97 structure, 128x128 tile) -- kept for gemm_wo.
// ---------------------------------------------------------------------------
static __device__ __forceinline__ void gemm_core(
    const ushort_t* __restrict__ A, const ushort_t* __restrict__ B,
    void* __restrict__ Cout, int N, int K, int bm, int bn,
    const float* __restrict__ xa, const float* __restrict__ LB,
    float lscale, int out_bf16, ushort_t* As, ushort_t* Bs)
{
    const int t = threadIdx.x;
    const int lane = t & 63;
    const int w = t >> 6;
    const int quad = lane >> 4;
    const int c = lane & 15;

    const int wm = (w & 1) * 64;
    const int wn = (w >> 1) * 64;

    f32x4 acc[4][4];
#pragma unroll
    for (int i = 0; i < 4; i++)
#pragma unroll
        for (int j = 0; j < 4; j++) acc[i][j] = (f32x4){0.f, 0.f, 0.f, 0.f};

    const int p0 = w * 64 + lane;
    const int p1 = 256 + w * 64 + lane;
    const int r0 = p0 >> 2, g0 = (p0 & 3) ^ ((p0 >> 3) & 3);
    const int r1 = p1 >> 2, g1 = (p1 & 3) ^ ((p1 >> 3) & 3);
    const ushort_t* gA0 = A + (size_t)(bm + r0) * K + g0 * 8;
    const ushort_t* gA1 = A + (size_t)(bm + r1) * K + g1 * 8;
    const ushort_t* gB0 = B + (size_t)(bn + r0) * K + g0 * 8;
    const ushort_t* gB1 = B + (size_t)(bn + r1) * K + g1 * 8;
    ushort_t* lA0 = As + (size_t)(w * 64) * 8;
    ushort_t* lA1 = As + (size_t)(256 + w * 64) * 8;
    ushort_t* lB0 = Bs + (size_t)(w * 64) * 8;
    ushort_t* lB1 = Bs + (size_t)(256 + w * 64) * 8;

    const int csw = quad ^ ((c >> 1) & 3);

    for (int k0 = 0; k0 < K; k0 += 32) {
        __syncthreads();
        gload_lds16(gA0 + k0, lA0);
        gload_lds16(gA1 + k0, lA1);
        gload_lds16(gB0 + k0, lB0);
        gload_lds16(gB1 + k0, lB1);
        __syncthreads();

        bf16x8 af[4], bfr[4];
#pragma unroll
        for (int mt = 0; mt < 4; mt++)
            af[mt] = *(const bf16x8*)&As[((wm + mt * 16 + c) * 4 + csw) * 8];
#pragma unroll
        for (int nt = 0; nt < 4; nt++)
            bfr[nt] = *(const bf16x8*)&Bs[((wn + nt * 16 + c) * 4 + csw) * 8];
#pragma unroll
        for (int mt = 0; mt < 4; mt++)
#pragma unroll
            for (int nt = 0; nt < 4; nt++)
                acc[mt][nt] = __builtin_amdgcn_mfma_f32_16x16x32_bf16(
                    af[mt], bfr[nt], acc[mt][nt], 0, 0, 0);
    }

    float lb[4][RANKL];
#pragma unroll
    for (int nt = 0; nt < 4; nt++) {
        int col = bn + wn + nt * 16 + c;
        float4 u = *(const float4*)&LB[(size_t)col * RANKL];
        float4 v = *(const float4*)&LB[(size_t)col * RANKL + 4];
        lb[nt][0] = u.x; lb[nt][1] = u.y; lb[nt][2] = u.z; lb[nt][3] = u.w;
        lb[nt][4] = v.x; lb[nt][5] = v.y; lb[nt][6] = v.z; lb[nt][7] = v.w;
    }
#pragma unroll
    for (int mt = 0; mt < 4; mt++) {
        float la[4][RANKL];
#pragma unroll
        for (int r = 0; r < 4; r++) {
            int row = bm + wm + mt * 16 + quad * 4 + r;
            float4 u = *(const float4*)&xa[(size_t)row * RANKL];
            float4 v = *(const float4*)&xa[(size_t)row * RANKL + 4];
            la[r][0] = u.x; la[r][1] = u.y; la[r][2] = u.z; la[r][3] = u.w;
            la[r][4] = v.x; la[r][5] = v.y; la[r][6] = v.z; la[r][7] = v.w;
        }
#pragma unroll
        for (int nt = 0; nt < 4; nt++) {
#pragma unroll
            for (int r = 0; r < 4; r++) {
                float s = 0.f;
#pragma unroll
                for (int k = 0; k < RANKL; k++) s += la[r][k] * lb[nt][k];
                float val = acc[mt][nt][r] + lscale * s;
                size_t row = bm + wm + mt * 16 + quad * 4 + r;
                size_t col = bn + wn + nt * 16 + c;
                if (out_bf16)
                    ((ushort_t*)Cout)[row * N + col] = f2bf(val);
                else
                    ((float*)Cout)[row * N + col] = val;
            }
        }
    }
}

// ---------------------------------------------------------------------------
// 256x256-tile 8-wave deep-pipelined QKV GEMM (T2+T3+T4+T5).
// ---------------------------------------------------------------------------
#define BKT 64
#define NKT (HIDDEN / BKT)   // 32

__global__ __launch_bounds__(512, 2) void gemm_qkv256(
    const ushort_t* __restrict__ A,
    const ushort_t* __restrict__ Wqb, const ushort_t* __restrict__ Wkb,
    const ushort_t* __restrict__ Wvb,
    ushort_t* __restrict__ q_lin, ushort_t* __restrict__ k_lin,
    ushort_t* __restrict__ v_lin,
    const float* __restrict__ xa_q, const float* __restrict__ xa_k,
    const float* __restrict__ xa_v,
    const float* __restrict__ qB, const float* __restrict__ kB,
    const float* __restrict__ vB)
{
    __shared__ __align__(16) ushort_t As[2][256 * BKT];   // 64 KiB
    __shared__ __align__(16) ushort_t Bs[2][256 * BKT];   // 64 KiB

    const int t = threadIdx.x;
    const int lane = t & 63;
    const int w = t >> 6;          // 0..7
    const int wm = w >> 2;         // 0..1  (M half)
    const int wn = w & 3;          // 0..3  (N quarter)
    const int quad = lane >> 4;
    const int c = lane & 15;
    const int c7 = c & 7;

    const int bc = blockIdx.y;
    const ushort_t* Bmat; ushort_t* Cout; const float* xa; const float* LB;
    int N, bn;
    if (bc < 8)       { Bmat = Wqb; Cout = q_lin; xa = xa_q; LB = qB; N = 2048; bn = bc * 256; }
    else if (bc < 12) { Bmat = Wkb; Cout = k_lin; xa = xa_k; LB = kB; N = 1024; bn = (bc - 8) * 256; }
    else              { Bmat = Wvb; Cout = v_lin; xa = xa_v; LB = vB; N = 1024; bn = (bc - 12) * 256; }
    const int bm = blockIdx.x * 256;

    // ---- staging addressing (chunk-XOR involution, linear LDS dest)
    const int r8  = lane >> 3;           // 0..7 row within 8-row group
    const int ksl = (lane & 7) ^ r8;     // swizzled k-chunk for this lane
    const int ga  = wn;                  // index within A staging group (wm)
    const int bh  = wn >> 1;             // B half this wave consumes
    const int gb  = wm * 2 + (wn & 1);   // index within B staging group (bh)

    const ushort_t* gAb = A    + (size_t)(bm + wm * 128 + ga * 8 + r8) * HIDDEN + ksl * 8;
    const ushort_t* gBb = Bmat + (size_t)(bn + bh * 128 + gb * 8 + r8) * HIDDEN + ksl * 8;
    const int lAoff = (wm * 128 + ga * 8) * BKT;   // + j*32*BKT
    const int lBoff = (bh * 128 + gb * 8) * BKT;

    // ---- prologue: tile 0 fully, tile 1 parts j=0..2
#pragma unroll
    for (int j = 0; j < 4; j++) {
        gload_lds16(gAb + (size_t)j * 32 * HIDDEN, &As[0][lAoff + j * 32 * BKT]);
        gload_lds16(gBb + (size_t)j * 32 * HIDDEN, &Bs[0][lBoff + j * 32 * BKT]);
    }
#pragma unroll
    for (int j = 0; j < 3; j++) {
        gload_lds16(gAb + (size_t)j * 32 * HIDDEN + BKT, &As[1][lAoff + j * 32 * BKT]);
        gload_lds16(gBb + (size_t)j * 32 * HIDDEN + BKT, &Bs[1][lBoff + j * 32 * BKT]);
    }

    f32x4 acc[8][4];
#pragma unroll
    for (int i = 0; i < 8; i++)
#pragma unroll
        for (int j = 0; j < 4; j++) acc[i][j] = (f32x4){0.f, 0.f, 0.f, 0.f};

#pragma unroll 1
    for (int T = 0; T < NKT; ++T) {
        const int cur = T & 1;
        const ushort_t* cA = As[cur];
        const ushort_t* cB = Bs[cur];
        bf16x8 bfr[4][2];

#pragma unroll
        for (int q = 0; q < 4; ++q) {
            if (q == 0) {
                asm volatile("s_waitcnt vmcnt(6)" ::: "memory");
            }
            __builtin_amdgcn_sched_barrier(0);
            __builtin_amdgcn_s_barrier();
            __builtin_amdgcn_sched_barrier(0);

            // ---- ds reads: A quadrant q (4 x b128); B all (8 x b128) at q==0
            bf16x8 af[2][2];
#pragma unroll
            for (int m2 = 0; m2 < 2; ++m2) {
                const int row = wm * 128 + (q * 2 + m2) * 16 + c;
#pragma unroll
                for (int kh = 0; kh < 2; ++kh)
                    af[m2][kh] = *(const bf16x8*)
                        &cA[row * BKT + (((kh * 4 + quad) ^ c7) * 8)];
            }
            if (q == 0) {
#pragma unroll
                for (int nt = 0; nt < 4; ++nt) {
                    const int rowb = wn * 64 + nt * 16 + c;
#pragma unroll
                    for (int kh = 0; kh < 2; ++kh)
                        bfr[nt][kh] = *(const bf16x8*)
                            &cB[rowb * BKT + (((kh * 4 + quad) ^ c7) * 8)];
                }
            }

            // ---- staging
            if (q == 0) {
                const int tl = T + 1;
                if (tl < NKT) {
                    gload_lds16(gAb + (size_t)3 * 32 * HIDDEN + (size_t)tl * BKT,
                                &As[cur ^ 1][lAoff + 3 * 32 * BKT]);
                    gload_lds16(gBb + (size_t)3 * 32 * HIDDEN + (size_t)tl * BKT,
                                &Bs[cur ^ 1][lBoff + 3 * 32 * BKT]);
                }
            } else {
                const int tl = T + 2;
                if (tl < NKT) {
                    const int j = q - 1;
                    gload_lds16(gAb + (size_t)j * 32 * HIDDEN + (size_t)tl * BKT,
                                &As[cur][lAoff + j * 32 * BKT]);
                    gload_lds16(gBb + (size_t)j * 32 * HIDDEN + (size_t)tl * BKT,
                                &Bs[cur][lBoff + j * 32 * BKT]);
                }
            }

            // ---- 16 MFMA: C-quadrant (32 rows x 64 cols) over K=64
            __builtin_amdgcn_s_setprio(1);
#pragma unroll
            for (int m2 = 0; m2 < 2; ++m2)
#pragma unroll
                for (int nt = 0; nt < 4; ++nt)
#pragma unroll
                    for (int kh = 0; kh < 2; ++kh)
                        acc[q * 2 + m2][nt] = __builtin_amdgcn_mfma_f32_16x16x32_bf16(
                            af[m2][kh], bfr[nt][kh], acc[q * 2 + m2][nt], 0, 0, 0);
            __builtin_amdgcn_s_setprio(0);
        }
    }

    // ---- epilogue: fused LoRA rank-8 + bf16 store
    float lb[4][RANKL];
#pragma unroll
    for (int nt = 0; nt < 4; nt++) {
        int col = bn + wn * 64 + nt * 16 + c;
        float4 u = *(const float4*)&LB[(size_t)col * RANKL];
        float4 v = *(const float4*)&LB[(size_t)col * RANKL + 4];
        lb[nt][0] = u.x; lb[nt][1] = u.y; lb[nt][2] = u.z; lb[nt][3] = u.w;
        lb[nt][4] = v.x; lb[nt][5] = v.y; lb[nt][6] = v.z; lb[nt][7] = v.w;
    }
#pragma unroll
    for (int mt = 0; mt < 8; mt++) {
        float la[4][RANKL];
#pragma unroll
        for (int r = 0; r < 4; r++) {
            int row = bm + wm * 128 + mt * 16 + quad * 4 + r;
            float4 u = *(const float4*)&xa[(size_t)row * RANKL];
            float4 v = *(const float4*)&xa[(size_t)row * RANKL + 4];
            la[r][0] = u.x; la[r][1] = u.y; la[r][2] = u.z; la[r][3] = u.w;
            la[r][4] = v.x; la[r][5] = v.y; la[r][6] = v.z; la[r][7] = v.w;
        }
#pragma unroll
        for (int nt = 0; nt < 4; nt++) {
#pragma unroll
            for (int r = 0; r < 4; r++) {
                float s = 0.f;
#pragma unroll
                for (int k = 0; k < RANKL; k++) s += la[r][k] * lb[nt][k];
                float val = acc[mt][nt][r] + LORA_SCALE * s;
                size_t row = bm + wm * 128 + mt * 16 + quad * 4 + r;
                size_t col = bn + wn * 64 + nt * 16 + c;
                Cout[row * N + col] = f2bf(val);
            }
        }
    }
}

// Output projection (fp32 out) -- m97-structure core (known-good)
__global__ __launch_bounds__(256) void gemm_wo(
    const ushort_t* __restrict__ A, const ushort_t* __restrict__ Wob,
    float* __restrict__ out, const float* __restrict__ xa_o,
    const float* __restrict__ oB)
{
    __shared__ ushort_t As[128 * 32];
    __shared__ ushort_t Bs[128 * 32];
    gemm_core(A, Wob, out, HIDDEN, NQ * HD, blockIdx.x * 128, blockIdx.y * 128,
              xa_o, oB, LORA_SCALE, 0, As, Bs);
}

// ---------------------------------------------------------------------------
// Fused relayout: blocks [0,4096) = RoPE for Q and K; blocks [4096,5120) =
// V transpose. Both depend only on gemm_qkv256 outputs -> co-execute.
// ---------------------------------------------------------------------------
__global__ __launch_bounds__(256) void reshape_fused(
    const ushort_t* __restrict__ qlin, const ushort_t* __restrict__ klin,
    ushort_t* __restrict__ qb, ushort_t* __restrict__ kb,
    const ushort_t* __restrict__ vlin, ushort_t* __restrict__ Vt)
{
    __shared__ ushort_t tile[64 * 72];
    int t = threadIdx.x;
    if (blockIdx.x < 4096) {
        int bs = blockIdx.x;
        int s = bs & (SEQ - 1);
        int b = bs >> 11;
        int p = t & 63;
        float inv = exp2f(-(float)p * 0.20762050593046f); // 10000^(-p/64)
        float ang = (float)s * inv;
        float cc = cosf(ang), si = sinf(ang);
#pragma unroll
        for (int j = 0; j < 6; j++) {
            int item = t + 256 * j;
            int hh = item >> 6;       // 0..23
            unsigned int pk;
            ushort_t* dst;
            if (hh < NQ) {
                pk = *(const unsigned int*)&qlin[(size_t)bs * (NQ * HD) + hh * HD + 2 * p];
                dst = qb + (((size_t)(b * NQ + hh) * SEQ) + s) * HD + 2 * p;
            } else {
                int kh = hh - NQ;
                pk = *(const unsigned int*)&klin[(size_t)bs * (NKV * HD) + kh * HD + 2 * p];
                dst = kb + (((size_t)(b * NKV + kh) * SEQ) + s) * HD + 2 * p;
            }
            float xr = bf2f((ushort_t)(pk & 0xffff));
            float xi = bf2f((ushort_t)(pk >> 16));
            float rr = xr * cc - xi * si;
            float ri = xr * si + xi * cc;
            *(unsigned int*)dst = ((unsigned int)f2bf(ri) << 16) | f2bf(rr);
        }
    } else {
        int idx = blockIdx.x - 4096;       // 0..1023
        int bk = idx >> 6;                 // 0..15 (b*8+kvh)
        int rem = idx & 63;
        int b = bk >> 3, kvh = bk & 7;
        int s0 = (rem >> 1) * 64, d0 = (rem & 1) * 64;
#pragma unroll
        for (int i = 0; i < 2; i++) {
            int id = t + 256 * i;
            int r = id >> 3, cc = id & 7;
            uint4 v = *(const uint4*)&vlin[(size_t)(b * SEQ + s0 + r) * (NKV * HD)
                                           + kvh * HD + d0 + cc * 8];
            *(uint4*)&tile[r * 72 + cc * 8] = v;
        }
        __syncthreads();
#pragma unroll
        for (int i = 0; i < 2; i++) {
            int id = t + 256 * i;
            int dr = id >> 3, sc = id & 7;
            ushort_t tmp[8];
#pragma unroll
            for (int e = 0; e < 8; e++) tmp[e] = tile[(sc * 8 + e) * 72 + dr];
            *(uint4*)&Vt[((size_t)(b * NKV + kvh) * HD + d0 + dr) * SEQ + s0 + sc * 8]
                = *(uint4*)tmp;
        }
    }
}

// ---------------------------------------------------------------------------
// MFMA flash attention v3 (BEST measured: 78.8 us).
// Block = 4 waves; handles q-tiles {a, 31-a} (64 rows each) sequentially ->
// exactly 33 key-tiles per block (uniform). Constant-max softmax. Ping-pong
// K/V staging, ONE barrier per tile. 512 blocks -> 2 co-resident uniform
// blocks per CU (sequential pairing keeps both alive to the end).
// Q,K: [b][h][s][128]; V: [b][kvh][d][s]; O: bf16 [b*s][h*128+d].
// ---------------------------------------------------------------------------
__global__ __launch_bounds__(256, 2) void attn_mfma3(
    const ushort_t* __restrict__ Q, const ushort_t* __restrict__ K,
    const ushort_t* __restrict__ V, ushort_t* __restrict__ O)
{
    __shared__ ushort_t Ks[2][64 * 128];    // 16 KB x2
    __shared__ ushort_t Vs[2][128 * 64];    // 16 KB x2
    __shared__ ushort_t Psh[4][16 * 68];    // 8.5 KB

    const int t = threadIdx.x;
    const int lane = t & 63;
    const int w = t >> 6;
    const int quad = lane >> 4;
    const int c = lane & 15;
    const int q4 = quad * 4;
    const int c7 = c & 7;

    const int head = blockIdx.x >> 4;     // b*NQ + h
    const int a = blockIdx.x & 15;
    const int h = head & (NQ - 1);
    const int b = head >> 4;
    const int kvh = b * NKV + (h >> 1);

    const ushort_t* Kg = K + (size_t)kvh * SEQ * HD;
    const ushort_t* Vg = V + (size_t)kvh * HD * SEQ;

    // staging address precompute (chunk id = t + 256*i)
    const ushort_t* gK[4]; const ushort_t* gV[4];
    int lo[4];
#pragma unroll
    for (int i = 0; i < 4; i++) {
        int cid = t + 256 * i;
        int kr = cid >> 4, kc = cid & 15;
        gK[i] = Kg + (size_t)kr * HD + ((kc ^ (kr & 7)) * 8);
        int vd = cid >> 3, vc = cid & 7;
        gV[i] = Vg + (size_t)vd * SEQ + ((vc ^ (vd & 7)) * 8);
        lo[i] = (i * 256 + (t & ~63)) * 8;
    }

#pragma unroll 1
    for (int half = 0; half < 2; half++) {
        const int qt = half ? (31 - a) : a;
        const int qb0 = qt * 64;
        const int myrow = qb0 + w * 16;       // wave's first q-row

        // Q fragments (A-operand), row = myrow + c
        const ushort_t* Qg = Q + ((size_t)head * SEQ + myrow + c) * HD;
        bf16x8 qf[4];
#pragma unroll
        for (int ch = 0; ch < 4; ch++)
            qf[ch] = *(const bf16x8*)(Qg + ch * 32 + quad * 8);

        f32x4 o[8];
#pragma unroll
        for (int i = 0; i < 8; i++) o[i] = (f32x4){0.f, 0.f, 0.f, 0.f};
        float lp[4] = {0.f, 0.f, 0.f, 0.f};

        const int ntiles = qt + 1;

        // prime tile 0 into buffer 0
#pragma unroll
        for (int i = 0; i < 4; i++) gload_lds16(gK[i], &Ks[0][lo[i]]);
#pragma unroll
        for (int i = 0; i < 4; i++) gload_lds16(gV[i], &Vs[0][lo[i]]);
        __syncthreads();

        for (int tile = 0; tile < ntiles; ++tile) {
            const int cur = tile & 1;
            if (tile + 1 < ntiles) {
                const int j1 = (tile + 1) * 64;
#pragma unroll
                for (int i = 0; i < 4; i++)
                    gload_lds16(gK[i] + (size_t)j1 * HD, &Ks[cur ^ 1][lo[i]]);
#pragma unroll
                for (int i = 0; i < 4; i++)
                    gload_lds16(gV[i] + j1, &Vs[cur ^ 1][lo[i]]);
            }

            // ---- QK^T
            f32x4 s[4];
#pragma unroll
            for (int tt = 0; tt < 4; tt++) s[tt] = (f32x4){0.f, 0.f, 0.f, 0.f};
#pragma unroll
            for (int tt = 0; tt < 4; tt++) {
                const int krow = tt * 16 + c;
#pragma unroll
                for (int ch = 0; ch < 4; ch++) {
                    bf16x8 kf = *(const bf16x8*)
                        &Ks[cur][krow * 128 + (((ch * 4 + quad) ^ c7) * 8)];
                    s[tt] = __builtin_amdgcn_mfma_f32_16x16x32_bf16(
                        qf[ch], kf, s[tt], 0, 0, 0);
                }
            }

            // ---- constant-max softmax: p = exp2(s*scale), masked -> 0
            const bool diag = (tile == qt);
            const int j0 = tile * 64;
#pragma unroll
            for (int r = 0; r < 4; r++) {
                const int row_g = myrow + q4 + r;
#pragma unroll
                for (int tt = 0; tt < 4; tt++) {
                    float p = exp2f(s[tt][r] * SM_SCALE);
                    if (diag && (j0 + tt * 16 + c > row_g)) p = 0.f;
                    Psh[w][(q4 + r) * 68 + tt * 16 + c] = f2bf(p);
                    lp[r] += p;
                }
            }

            // ---- P fragments (A-layout)
            bf16x8 pf[2];
#pragma unroll
            for (int ch = 0; ch < 2; ch++) {
                int base = c * 68 + ch * 32 + quad * 8;
                uint2 aa = *(const uint2*)&Psh[w][base];
                uint2 bb = *(const uint2*)&Psh[w][base + 4];
                uint4 u; u.x = aa.x; u.y = aa.y; u.z = bb.x; u.w = bb.y;
                pf[ch] = __builtin_bit_cast(bf16x8, u);
            }

            // ---- PV
#pragma unroll
            for (int dt = 0; dt < 8; dt++) {
                const int vrow = dt * 16 + c;
#pragma unroll
                for (int ch = 0; ch < 2; ch++) {
                    bf16x8 vf = *(const bf16x8*)
                        &Vs[cur][vrow * 64 + (((ch * 4 + quad) ^ c7) * 8)];
                    o[dt] = __builtin_amdgcn_mfma_f32_16x16x32_bf16(
                        pf[ch], vf, o[dt], 0, 0, 0);
                }
            }
            __syncthreads();   // next tile staged + everyone done with cur
        }

        // ---- epilogue: reduce l over the 16 c-lanes, normalize, store
        float inv[4];
#pragma unroll
        for (int r = 0; r < 4; r++) {
            float v = lp[r];
            v += __shfl_xor(v, 1);
            v += __shfl_xor(v, 2);
            v += __shfl_xor(v, 4);
            v += __shfl_xor(v, 8);
            inv[r] = 1.f / v;
        }
        size_t base = ((size_t)b * SEQ + myrow + q4) * (NQ * HD) + h * HD + c;
#pragma unroll
        for (int r = 0; r < 4; r++)
#pragma unroll
            for (int dt = 0; dt < 8; dt++)
                O[base + (size_t)r * (NQ * HD) + dt * 16] =
                    f2bf(o[dt][r] * inv[r]);
    }
}

// ---------------------------------------------------------------------------
// Launch
// ---------------------------------------------------------------------------
extern "C" void kernel_launch(void* const* d_in, const int* in_sizes, int n_in,
                              void* d_out, int out_size, void* d_ws, size_t ws_size,
                              hipStream_t stream)
{
    const float* x  = (const float*)d_in[0];
    const float* Wq = (const float*)d_in[1];
    const float* Wk = (const float*)d_in[2];
    const float* Wv = (const float*)d_in[3];
    const float* Wo = (const float*)d_in[4];
    const float* qA = (const float*)d_in[5];
    const float* qB = (const float*)d_in[6];
    const float* kA = (const float*)d_in[7];
    const float* kB = (const float*)d_in[8];
    const float* vA = (const float*)d_in[9];
    const float* vB = (const float*)d_in[10];
    const float* oA = (const float*)d_in[11];
    const float* oB = (const float*)d_in[12];
    float* out = (float*)d_out;
    float* ws = (float*)d_ws;

    const int M = BATCH * SEQ;           // 4096

    float* xa_q = ws;
    float* xa_k = ws + 32768;
    float* xa_v = ws + 65536;
    float* xa_o = ws + 98304;
    ushort_t* q_lin = (ushort_t*)(ws + 131072);    // bf16 4096x2048
    ushort_t* k_lin = (ushort_t*)(ws + 4325376);   // bf16 4096x1024
    ushort_t* v_lin = (ushort_t*)(ws + 6422528);   // bf16 4096x1024
    ushort_t* qb    = (ushort_t*)(ws + 8519680);   // bf16 [B][16][S][128]
    ushort_t* kb    = (ushort_t*)(ws + 12713984);  // bf16 [B][8][S][128]
    ushort_t* vtb   = (ushort_t*)(ws + 14811136);  // bf16 [B][8][128][S]
    ushort_t* xbf   = (ushort_t*)(ws + 16908288);  // bf16 4096x2048
    ushort_t* Wqb   = (ushort_t*)(ws + 21102592);
    ushort_t* Wkb   = (ushort_t*)(ws + 23199744);
    ushort_t* Wvb   = (ushort_t*)(ws + 24248320);
    ushort_t* Wob   = (ushort_t*)(ws + 25296896);
    ushort_t* attn_out = q_lin;          // q_lin consumed before attention

    // fused prologue: x cast + q/k/v LoRA-A  ||  all weight casts
    prep_fused<<<4096 + 6144, 256, 0, stream>>>(
        x, xbf, qA, kA, vA, xa_q, xa_k, xa_v,
        Wq, Wk, Wv, Wo, Wqb, Wkb, Wvb, Wob);

    // fused QKV projection: 256^2 tiles, deep pipeline, fused LoRA
    gemm_qkv256<<<dim3(M / 256, 16), 512, 0, stream>>>(
        xbf, Wqb, Wkb, Wvb, q_lin, k_lin, v_lin,
        xa_q, xa_k, xa_v, qB, kB, vB);

    // fused relayout: RoPE q,k  ||  V transpose
    reshape_fused<<<4096 + 1024, 256, 0, stream>>>(
        q_lin, k_lin, qb, kb, v_lin, vtb);

    // flash attention (uniform 33-tile blocks, 2 co-resident blocks/CU)
    attn_mfma3<<<512, 256, 0, stream>>>(qb, kb, vtb, attn_out);

    // output projection with fused o-LoRA
    lora_xa_bf16<<<M, 256, 0, stream>>>(attn_out, oA, xa_o, NQ * HD);
    gemm_wo<<<dim3(M / 128, HIDDEN / 128), 256, 0, stream>>>(
        attn_out, Wob, out, xa_o, oB);
}

// Round 6
// 371.848 us; speedup vs baseline: 1.1694x; 1.0467x over previous
//
#include <hip/hip_runtime.h>
#include <hip/hip_bf16.h>
#include <cmath>

// Problem constants
#define HIDDEN 2048
#define SEQ 2048
#define BATCH 2
#define NQ 16
#define NKV 8
#define HD 128
#define RANKL 8
#define LORA_SCALE 2.0f
#define INV_SQRT_D 0.08838834764831845f
#define LOG2E 1.4426950408889634f
#define SM_SCALE (INV_SQRT_D * LOG2E)

typedef unsigned short ushort_t;
typedef __bf16 bf16x8 __attribute__((ext_vector_type(8)));
typedef float f32x4 __attribute__((ext_vector_type(4)));

static __device__ __forceinline__ ushort_t f2bf(float f) {
    __hip_bfloat16 h = __float2bfloat16(f);
    return *(ushort_t*)&h;
}
static __device__ __forceinline__ float bf2f(ushort_t u) {
    unsigned int v = ((unsigned int)u) << 16;
    return __builtin_bit_cast(float, v);
}
static __device__ __forceinline__ void gload_lds16(const ushort_t* g, ushort_t* l) {
    __builtin_amdgcn_global_load_lds(
        (const __attribute__((address_space(1))) unsigned int*)g,
        (__attribute__((address_space(3))) unsigned int*)l, 16, 0, 0);
}
static __device__ __forceinline__ bf16x8 pack8(float4 a, float4 b) {
    uint4 u;
    u.x = (unsigned int)f2bf(a.x) | ((unsigned int)f2bf(a.y) << 16);
    u.y = (unsigned int)f2bf(a.z) | ((unsigned int)f2bf(a.w) << 16);
    u.z = (unsigned int)f2bf(b.x) | ((unsigned int)f2bf(b.y) << 16);
    u.w = (unsigned int)f2bf(b.z) | ((unsigned int)f2bf(b.w) << 16);
    return __builtin_bit_cast(bf16x8, u);
}

// ---------------------------------------------------------------------------
// Fused prologue:
//   blocks [0,4096):     x -> bf16 cast (pure streaming)
//   blocks [4096,10240): all four weight casts
//   blocks [10240,10496): xa = x @ [qA;kA;vA]^T via MFMA (16 rows/block,
//                         4 waves split K=2048 into 512 each, LDS reduce)
// ---------------------------------------------------------------------------
__global__ __launch_bounds__(256) void prep_fused(
    const float* __restrict__ X, ushort_t* __restrict__ Xbf,
    const float* __restrict__ qA, const float* __restrict__ kA,
    const float* __restrict__ vA,
    float* __restrict__ xa_q, float* __restrict__ xa_k,
    float* __restrict__ xa_v,
    const float* __restrict__ Wq, const float* __restrict__ Wk,
    const float* __restrict__ Wv, const float* __restrict__ Wo,
    ushort_t* __restrict__ Wqb, ushort_t* __restrict__ Wkb,
    ushort_t* __restrict__ Wvb, ushort_t* __restrict__ Wob)
{
    __shared__ f32x4 red[4][2][64];
    const int t = threadIdx.x;
    const int bid = blockIdx.x;

    if (bid < 4096) {
        // ---- x cast: one row per block, 8 elems/thread
        int c0 = t * 8;
        const float* xr = X + (size_t)bid * HIDDEN + c0;
        float4 a = *(const float4*)xr;
        float4 b = *(const float4*)(xr + 4);
        uint4 o;
        o.x = (unsigned int)f2bf(a.x) | ((unsigned int)f2bf(a.y) << 16);
        o.y = (unsigned int)f2bf(a.z) | ((unsigned int)f2bf(a.w) << 16);
        o.z = (unsigned int)f2bf(b.x) | ((unsigned int)f2bf(b.y) << 16);
        o.w = (unsigned int)f2bf(b.z) | ((unsigned int)f2bf(b.w) << 16);
        *(uint4*)(Xbf + (size_t)bid * HIDDEN + c0) = o;
    } else if (bid < 10240) {
        // ---- weight casts
        size_t i = (size_t)(bid - 4096) * 256 + t;   // 0..1572863
        const float* src; ushort_t* dst; size_t j;
        if (i < 524288)       { src = Wq; dst = Wqb; j = i; }
        else if (i < 786432)  { src = Wk; dst = Wkb; j = i - 524288; }
        else if (i < 1048576) { src = Wv; dst = Wvb; j = i - 786432; }
        else                  { src = Wo; dst = Wob; j = i - 1048576; }
        const float4* p = (const float4*)src + j * 2;
        float4 a = p[0], b = p[1];
        uint4 o;
        o.x = (unsigned int)f2bf(a.x) | ((unsigned int)f2bf(a.y) << 16);
        o.y = (unsigned int)f2bf(a.z) | ((unsigned int)f2bf(a.w) << 16);
        o.z = (unsigned int)f2bf(b.x) | ((unsigned int)f2bf(b.y) << 16);
        o.w = (unsigned int)f2bf(b.z) | ((unsigned int)f2bf(b.w) << 16);
        *(uint4*)(dst + j * 8) = o;
    } else {
        // ---- xa MFMA: 16 rows, cols 0..23 = [qA(8); kA(8); vA(8)]
        const int m0 = (bid - 10240) * 16;
        const int lane = t & 63;
        const int w = t >> 6;
        const int c = lane & 15;
        const int quad = lane >> 4;

        // B-operand row pointers (col = nt*16 + c)
        const float* b0 = (c < 8) ? (qA + (size_t)c * HIDDEN)
                                  : (kA + (size_t)(c - 8) * HIDDEN);
        const float* b1 = vA + (size_t)(c & 7) * HIDDEN;
        const bool b1v = (c < 8);
        const float* ax = X + (size_t)(m0 + c) * HIDDEN;

        f32x4 acc0 = (f32x4){0.f, 0.f, 0.f, 0.f};
        f32x4 acc1 = (f32x4){0.f, 0.f, 0.f, 0.f};
        const int kbase = w * 512 + quad * 8;
#pragma unroll
        for (int ks = 0; ks < 16; ++ks) {
            const int k = kbase + ks * 32;
            float4 x0 = *(const float4*)&ax[k];
            float4 x1 = *(const float4*)&ax[k + 4];
            float4 p0a = *(const float4*)&b0[k];
            float4 p0b = *(const float4*)&b0[k + 4];
            float4 p1a = {0.f, 0.f, 0.f, 0.f}, p1b = {0.f, 0.f, 0.f, 0.f};
            if (b1v) { p1a = *(const float4*)&b1[k]; p1b = *(const float4*)&b1[k + 4]; }
            bf16x8 af = pack8(x0, x1);
            bf16x8 bf0 = pack8(p0a, p0b);
            bf16x8 bf1 = pack8(p1a, p1b);
            acc0 = __builtin_amdgcn_mfma_f32_16x16x32_bf16(af, bf0, acc0, 0, 0, 0);
            acc1 = __builtin_amdgcn_mfma_f32_16x16x32_bf16(af, bf1, acc1, 0, 0, 0);
        }
        red[w][0][lane] = acc0;
        red[w][1][lane] = acc1;
        __syncthreads();
        if (t < 64) {
#pragma unroll
            for (int nt = 0; nt < 2; ++nt) {
                f32x4 s = red[0][nt][t];
#pragma unroll
                for (int ww = 1; ww < 4; ++ww) {
                    f32x4 o = red[ww][nt][t];
                    s[0] += o[0]; s[1] += o[1]; s[2] += o[2]; s[3] += o[3];
                }
                int col = nt * 16 + (t & 15);
                if (col < 24) {
                    float* dst = (col < 8) ? xa_q : (col < 16) ? xa_k : xa_v;
                    int cc = col & 7;
                    int row0 = m0 + (t >> 4) * 4;
#pragma unroll
                    for (int r = 0; r < 4; ++r)
                        dst[(size_t)(row0 + r) * RANKL + cc] = s[r];
                }
            }
        }
    }
}

// ---------------------------------------------------------------------------
// o-LoRA A-projection via MFMA: xa_o = attn_out @ oA^T.
// 16 rows/block, 4 waves split K=2048, LDS reduce. A is bf16 (direct loads).
// ---------------------------------------------------------------------------
__global__ __launch_bounds__(256) void lora_o_mfma(
    const ushort_t* __restrict__ Xo, const float* __restrict__ oA,
    float* __restrict__ xa_o)
{
    __shared__ f32x4 red[4][64];
    const int t = threadIdx.x;
    const int lane = t & 63;
    const int w = t >> 6;
    const int c = lane & 15;
    const int quad = lane >> 4;
    const int m0 = blockIdx.x * 16;

    const ushort_t* ax = Xo + (size_t)(m0 + c) * (NQ * HD);
    const float* b0 = oA + (size_t)(c & 7) * (NQ * HD);
    const bool bv = (c < 8);

    f32x4 acc = (f32x4){0.f, 0.f, 0.f, 0.f};
    const int kbase = w * 512 + quad * 8;
#pragma unroll
    for (int ks = 0; ks < 16; ++ks) {
        const int k = kbase + ks * 32;
        bf16x8 af = *(const bf16x8*)&ax[k];
        float4 pa = {0.f, 0.f, 0.f, 0.f}, pb = {0.f, 0.f, 0.f, 0.f};
        if (bv) { pa = *(const float4*)&b0[k]; pb = *(const float4*)&b0[k + 4]; }
        bf16x8 bf = pack8(pa, pb);
        acc = __builtin_amdgcn_mfma_f32_16x16x32_bf16(af, bf, acc, 0, 0, 0);
    }
    red[w][lane] = acc;
    __syncthreads();
    if (t < 64) {
        f32x4 s = red[0][t];
#pragma unroll
        for (int ww = 1; ww < 4; ++ww) {
            f32x4 o = red[ww][t];
            s[0] += o[0]; s[1] += o[1]; s[2] += o[2]; s[3] += o[3];
        }
        int col = t & 15;
        if (col < 8) {
            int row0 = m0 + (t >> 4) * 4;
#pragma unroll
            for (int r = 0; r < 4; ++r)
                xa_o[(size_t)(row0 + r) * RANKL + col] = s[r];
        }
    }
}

// ---------------------------------------------------------------------------
// bf16 MFMA GEMM core (m97 structure, 128x128 tile) -- kept for gemm_wo.
// ---------------------------------------------------------------------------
static __device__ __forceinline__ void gemm_core(
    const ushort_t* __restrict__ A, const ushort_t* __restrict__ B,
    void* __restrict__ Cout, int N, int K, int bm, int bn,
    const float* __restrict__ xa, const float* __restrict__ LB,
    float lscale, int out_bf16, ushort_t* As, ushort_t* Bs)
{
    const int t = threadIdx.x;
    const int lane = t & 63;
    const int w = t >> 6;
    const int quad = lane >> 4;
    const int c = lane & 15;

    const int wm = (w & 1) * 64;
    const int wn = (w >> 1) * 64;

    f32x4 acc[4][4];
#pragma unroll
    for (int i = 0; i < 4; i++)
#pragma unroll
        for (int j = 0; j < 4; j++) acc[i][j] = (f32x4){0.f, 0.f, 0.f, 0.f};

    const int p0 = w * 64 + lane;
    const int p1 = 256 + w * 64 + lane;
    const int r0 = p0 >> 2, g0 = (p0 & 3) ^ ((p0 >> 3) & 3);
    const int r1 = p1 >> 2, g1 = (p1 & 3) ^ ((p1 >> 3) & 3);
    const ushort_t* gA0 = A + (size_t)(bm + r0) * K + g0 * 8;
    const ushort_t* gA1 = A + (size_t)(bm + r1) * K + g1 * 8;
    const ushort_t* gB0 = B + (size_t)(bn + r0) * K + g0 * 8;
    const ushort_t* gB1 = B + (size_t)(bn + r1) * K + g1 * 8;
    ushort_t* lA0 = As + (size_t)(w * 64) * 8;
    ushort_t* lA1 = As + (size_t)(256 + w * 64) * 8;
    ushort_t* lB0 = Bs + (size_t)(w * 64) * 8;
    ushort_t* lB1 = Bs + (size_t)(256 + w * 64) * 8;

    const int csw = quad ^ ((c >> 1) & 3);

    for (int k0 = 0; k0 < K; k0 += 32) {
        __syncthreads();
        gload_lds16(gA0 + k0, lA0);
        gload_lds16(gA1 + k0, lA1);
        gload_lds16(gB0 + k0, lB0);
        gload_lds16(gB1 + k0, lB1);
        __syncthreads();

        bf16x8 af[4], bfr[4];
#pragma unroll
        for (int mt = 0; mt < 4; mt++)
            af[mt] = *(const bf16x8*)&As[((wm + mt * 16 + c) * 4 + csw) * 8];
#pragma unroll
        for (int nt = 0; nt < 4; nt++)
            bfr[nt] = *(const bf16x8*)&Bs[((wn + nt * 16 + c) * 4 + csw) * 8];
#pragma unroll
        for (int mt = 0; mt < 4; mt++)
#pragma unroll
            for (int nt = 0; nt < 4; nt++)
                acc[mt][nt] = __builtin_amdgcn_mfma_f32_16x16x32_bf16(
                    af[mt], bfr[nt], acc[mt][nt], 0, 0, 0);
    }

    float lb[4][RANKL];
#pragma unroll
    for (int nt = 0; nt < 4; nt++) {
        int col = bn + wn + nt * 16 + c;
        float4 u = *(const float4*)&LB[(size_t)col * RANKL];
        float4 v = *(const float4*)&LB[(size_t)col * RANKL + 4];
        lb[nt][0] = u.x; lb[nt][1] = u.y; lb[nt][2] = u.z; lb[nt][3] = u.w;
        lb[nt][4] = v.x; lb[nt][5] = v.y; lb[nt][6] = v.z; lb[nt][7] = v.w;
    }
#pragma unroll
    for (int mt = 0; mt < 4; mt++) {
        float la[4][RANKL];
#pragma unroll
        for (int r = 0; r < 4; r++) {
            int row = bm + wm + mt * 16 + quad * 4 + r;
            float4 u = *(const float4*)&xa[(size_t)row * RANKL];
            float4 v = *(const float4*)&xa[(size_t)row * RANKL + 4];
            la[r][0] = u.x; la[r][1] = u.y; la[r][2] = u.z; la[r][3] = u.w;
            la[r][4] = v.x; la[r][5] = v.y; la[r][6] = v.z; la[r][7] = v.w;
        }
#pragma unroll
        for (int nt = 0; nt < 4; nt++) {
#pragma unroll
            for (int r = 0; r < 4; r++) {
                float s = 0.f;
#pragma unroll
                for (int k = 0; k < RANKL; k++) s += la[r][k] * lb[nt][k];
                float val = acc[mt][nt][r] + lscale * s;
                size_t row = bm + wm + mt * 16 + quad * 4 + r;
                size_t col = bn + wn + nt * 16 + c;
                if (out_bf16)
                    ((ushort_t*)Cout)[row * N + col] = f2bf(val);
                else
                    ((float*)Cout)[row * N + col] = val;
            }
        }
    }
}

// ---------------------------------------------------------------------------
// 256x256-tile 8-wave deep-pipelined QKV GEMM (T2+T3+T4+T5).
// ---------------------------------------------------------------------------
#define BKT 64
#define NKT (HIDDEN / BKT)   // 32

__global__ __launch_bounds__(512, 2) void gemm_qkv256(
    const ushort_t* __restrict__ A,
    const ushort_t* __restrict__ Wqb, const ushort_t* __restrict__ Wkb,
    const ushort_t* __restrict__ Wvb,
    ushort_t* __restrict__ q_lin, ushort_t* __restrict__ k_lin,
    ushort_t* __restrict__ v_lin,
    const float* __restrict__ xa_q, const float* __restrict__ xa_k,
    const float* __restrict__ xa_v,
    const float* __restrict__ qB, const float* __restrict__ kB,
    const float* __restrict__ vB)
{
    __shared__ __align__(16) ushort_t As[2][256 * BKT];   // 64 KiB
    __shared__ __align__(16) ushort_t Bs[2][256 * BKT];   // 64 KiB

    const int t = threadIdx.x;
    const int lane = t & 63;
    const int w = t >> 6;          // 0..7
    const int wm = w >> 2;         // 0..1  (M half)
    const int wn = w & 3;          // 0..3  (N quarter)
    const int quad = lane >> 4;
    const int c = lane & 15;
    const int c7 = c & 7;

    const int bc = blockIdx.y;
    const ushort_t* Bmat; ushort_t* Cout; const float* xa; const float* LB;
    int N, bn;
    if (bc < 8)       { Bmat = Wqb; Cout = q_lin; xa = xa_q; LB = qB; N = 2048; bn = bc * 256; }
    else if (bc < 12) { Bmat = Wkb; Cout = k_lin; xa = xa_k; LB = kB; N = 1024; bn = (bc - 8) * 256; }
    else              { Bmat = Wvb; Cout = v_lin; xa = xa_v; LB = vB; N = 1024; bn = (bc - 12) * 256; }
    const int bm = blockIdx.x * 256;

    // ---- staging addressing (chunk-XOR involution, linear LDS dest)
    const int r8  = lane >> 3;           // 0..7 row within 8-row group
    const int ksl = (lane & 7) ^ r8;     // swizzled k-chunk for this lane
    const int ga  = wn;                  // index within A staging group (wm)
    const int bh  = wn >> 1;             // B half this wave consumes
    const int gb  = wm * 2 + (wn & 1);   // index within B staging group (bh)

    const ushort_t* gAb = A    + (size_t)(bm + wm * 128 + ga * 8 + r8) * HIDDEN + ksl * 8;
    const ushort_t* gBb = Bmat + (size_t)(bn + bh * 128 + gb * 8 + r8) * HIDDEN + ksl * 8;
    const int lAoff = (wm * 128 + ga * 8) * BKT;   // + j*32*BKT
    const int lBoff = (bh * 128 + gb * 8) * BKT;

    // ---- prologue: tile 0 fully, tile 1 parts j=0..2
#pragma unroll
    for (int j = 0; j < 4; j++) {
        gload_lds16(gAb + (size_t)j * 32 * HIDDEN, &As[0][lAoff + j * 32 * BKT]);
        gload_lds16(gBb + (size_t)j * 32 * HIDDEN, &Bs[0][lBoff + j * 32 * BKT]);
    }
#pragma unroll
    for (int j = 0; j < 3; j++) {
        gload_lds16(gAb + (size_t)j * 32 * HIDDEN + BKT, &As[1][lAoff + j * 32 * BKT]);
        gload_lds16(gBb + (size_t)j * 32 * HIDDEN + BKT, &Bs[1][lBoff + j * 32 * BKT]);
    }

    f32x4 acc[8][4];
#pragma unroll
    for (int i = 0; i < 8; i++)
#pragma unroll
        for (int j = 0; j < 4; j++) acc[i][j] = (f32x4){0.f, 0.f, 0.f, 0.f};

#pragma unroll 1
    for (int T = 0; T < NKT; ++T) {
        const int cur = T & 1;
        const ushort_t* cA = As[cur];
        const ushort_t* cB = Bs[cur];
        bf16x8 bfr[4][2];

#pragma unroll
        for (int q = 0; q < 4; ++q) {
            if (q == 0) {
                asm volatile("s_waitcnt vmcnt(6)" ::: "memory");
            }
            __builtin_amdgcn_sched_barrier(0);
            __builtin_amdgcn_s_barrier();
            __builtin_amdgcn_sched_barrier(0);

            // ---- ds reads: A quadrant q (4 x b128); B all (8 x b128) at q==0
            bf16x8 af[2][2];
#pragma unroll
            for (int m2 = 0; m2 < 2; ++m2) {
                const int row = wm * 128 + (q * 2 + m2) * 16 + c;
#pragma unroll
                for (int kh = 0; kh < 2; ++kh)
                    af[m2][kh] = *(const bf16x8*)
                        &cA[row * BKT + (((kh * 4 + quad) ^ c7) * 8)];
            }
            if (q == 0) {
#pragma unroll
                for (int nt = 0; nt < 4; ++nt) {
                    const int rowb = wn * 64 + nt * 16 + c;
#pragma unroll
                    for (int kh = 0; kh < 2; ++kh)
                        bfr[nt][kh] = *(const bf16x8*)
                            &cB[rowb * BKT + (((kh * 4 + quad) ^ c7) * 8)];
                }
            }

            // ---- staging
            if (q == 0) {
                const int tl = T + 1;
                if (tl < NKT) {
                    gload_lds16(gAb + (size_t)3 * 32 * HIDDEN + (size_t)tl * BKT,
                                &As[cur ^ 1][lAoff + 3 * 32 * BKT]);
                    gload_lds16(gBb + (size_t)3 * 32 * HIDDEN + (size_t)tl * BKT,
                                &Bs[cur ^ 1][lBoff + 3 * 32 * BKT]);
                }
            } else {
                const int tl = T + 2;
                if (tl < NKT) {
                    const int j = q - 1;
                    gload_lds16(gAb + (size_t)j * 32 * HIDDEN + (size_t)tl * BKT,
                                &As[cur][lAoff + j * 32 * BKT]);
                    gload_lds16(gBb + (size_t)j * 32 * HIDDEN + (size_t)tl * BKT,
                                &Bs[cur][lBoff + j * 32 * BKT]);
                }
            }

            // ---- 16 MFMA: C-quadrant (32 rows x 64 cols) over K=64
            __builtin_amdgcn_s_setprio(1);
#pragma unroll
            for (int m2 = 0; m2 < 2; ++m2)
#pragma unroll
                for (int nt = 0; nt < 4; ++nt)
#pragma unroll
                    for (int kh = 0; kh < 2; ++kh)
                        acc[q * 2 + m2][nt] = __builtin_amdgcn_mfma_f32_16x16x32_bf16(
                            af[m2][kh], bfr[nt][kh], acc[q * 2 + m2][nt], 0, 0, 0);
            __builtin_amdgcn_s_setprio(0);
        }
    }

    // ---- epilogue: fused LoRA rank-8 + bf16 store
    float lb[4][RANKL];
#pragma unroll
    for (int nt = 0; nt < 4; nt++) {
        int col = bn + wn * 64 + nt * 16 + c;
        float4 u = *(const float4*)&LB[(size_t)col * RANKL];
        float4 v = *(const float4*)&LB[(size_t)col * RANKL + 4];
        lb[nt][0] = u.x; lb[nt][1] = u.y; lb[nt][2] = u.z; lb[nt][3] = u.w;
        lb[nt][4] = v.x; lb[nt][5] = v.y; lb[nt][6] = v.z; lb[nt][7] = v.w;
    }
#pragma unroll
    for (int mt = 0; mt < 8; mt++) {
        float la[4][RANKL];
#pragma unroll
        for (int r = 0; r < 4; r++) {
            int row = bm + wm * 128 + mt * 16 + quad * 4 + r;
            float4 u = *(const float4*)&xa[(size_t)row * RANKL];
            float4 v = *(const float4*)&xa[(size_t)row * RANKL + 4];
            la[r][0] = u.x; la[r][1] = u.y; la[r][2] = u.z; la[r][3] = u.w;
            la[r][4] = v.x; la[r][5] = v.y; la[r][6] = v.z; la[r][7] = v.w;
        }
#pragma unroll
        for (int nt = 0; nt < 4; nt++) {
#pragma unroll
            for (int r = 0; r < 4; r++) {
                float s = 0.f;
#pragma unroll
                for (int k = 0; k < RANKL; k++) s += la[r][k] * lb[nt][k];
                float val = acc[mt][nt][r] + LORA_SCALE * s;
                size_t row = bm + wm * 128 + mt * 16 + quad * 4 + r;
                size_t col = bn + wn * 64 + nt * 16 + c;
                Cout[row * N + col] = f2bf(val);
            }
        }
    }
}

// Output projection (fp32 out) -- m97-structure core (known-good)
__global__ __launch_bounds__(256) void gemm_wo(
    const ushort_t* __restrict__ A, const ushort_t* __restrict__ Wob,
    float* __restrict__ out, const float* __restrict__ xa_o,
    const float* __restrict__ oB)
{
    __shared__ ushort_t As[128 * 32];
    __shared__ ushort_t Bs[128 * 32];
    gemm_core(A, Wob, out, HIDDEN, NQ * HD, blockIdx.x * 128, blockIdx.y * 128,
              xa_o, oB, LORA_SCALE, 0, As, Bs);
}

// ---------------------------------------------------------------------------
// Fused relayout: blocks [0,4096) = RoPE for Q and K; blocks [4096,5120) =
// V transpose. Both depend only on gemm_qkv256 outputs -> co-execute.
// ---------------------------------------------------------------------------
__global__ __launch_bounds__(256) void reshape_fused(
    const ushort_t* __restrict__ qlin, const ushort_t* __restrict__ klin,
    ushort_t* __restrict__ qb, ushort_t* __restrict__ kb,
    const ushort_t* __restrict__ vlin, ushort_t* __restrict__ Vt)
{
    __shared__ ushort_t tile[64 * 72];
    int t = threadIdx.x;
    if (blockIdx.x < 4096) {
        int bs = blockIdx.x;
        int s = bs & (SEQ - 1);
        int b = bs >> 11;
        int p = t & 63;
        float inv = exp2f(-(float)p * 0.20762050593046f); // 10000^(-p/64)
        float ang = (float)s * inv;
        float cc = cosf(ang), si = sinf(ang);
#pragma unroll
        for (int j = 0; j < 6; j++) {
            int item = t + 256 * j;
            int hh = item >> 6;       // 0..23
            unsigned int pk;
            ushort_t* dst;
            if (hh < NQ) {
                pk = *(const unsigned int*)&qlin[(size_t)bs * (NQ * HD) + hh * HD + 2 * p];
                dst = qb + (((size_t)(b * NQ + hh) * SEQ) + s) * HD + 2 * p;
            } else {
                int kh = hh - NQ;
                pk = *(const unsigned int*)&klin[(size_t)bs * (NKV * HD) + kh * HD + 2 * p];
                dst = kb + (((size_t)(b * NKV + kh) * SEQ) + s) * HD + 2 * p;
            }
            float xr = bf2f((ushort_t)(pk & 0xffff));
            float xi = bf2f((ushort_t)(pk >> 16));
            float rr = xr * cc - xi * si;
            float ri = xr * si + xi * cc;
            *(unsigned int*)dst = ((unsigned int)f2bf(ri) << 16) | f2bf(rr);
        }
    } else {
        int idx = blockIdx.x - 4096;       // 0..1023
        int bk = idx >> 6;                 // 0..15 (b*8+kvh)
        int rem = idx & 63;
        int b = bk >> 3, kvh = bk & 7;
        int s0 = (rem >> 1) * 64, d0 = (rem & 1) * 64;
#pragma unroll
        for (int i = 0; i < 2; i++) {
            int id = t + 256 * i;
            int r = id >> 3, cc = id & 7;
            uint4 v = *(const uint4*)&vlin[(size_t)(b * SEQ + s0 + r) * (NKV * HD)
                                           + kvh * HD + d0 + cc * 8];
            *(uint4*)&tile[r * 72 + cc * 8] = v;
        }
        __syncthreads();
#pragma unroll
        for (int i = 0; i < 2; i++) {
            int id = t + 256 * i;
            int dr = id >> 3, sc = id & 7;
            ushort_t tmp[8];
#pragma unroll
            for (int e = 0; e < 8; e++) tmp[e] = tile[(sc * 8 + e) * 72 + dr];
            *(uint4*)&Vt[((size_t)(b * NKV + kvh) * HD + d0 + dr) * SEQ + s0 + sc * 8]
                = *(uint4*)tmp;
        }
    }
}

// ---------------------------------------------------------------------------
// MFMA flash attention v3 (BEST measured: 78.8 us).
// Block = 4 waves; handles q-tiles {a, 31-a} (64 rows each) sequentially ->
// exactly 33 key-tiles per block (uniform). Constant-max softmax. Ping-pong
// K/V staging, ONE barrier per tile. 512 blocks -> 2 co-resident uniform
// blocks per CU (sequential pairing keeps both alive to the end).
// Q,K: [b][h][s][128]; V: [b][kvh][d][s]; O: bf16 [b*s][h*128+d].
// ---------------------------------------------------------------------------
__global__ __launch_bounds__(256, 2) void attn_mfma3(
    const ushort_t* __restrict__ Q, const ushort_t* __restrict__ K,
    const ushort_t* __restrict__ V, ushort_t* __restrict__ O)
{
    __shared__ ushort_t Ks[2][64 * 128];    // 16 KB x2
    __shared__ ushort_t Vs[2][128 * 64];    // 16 KB x2
    __shared__ ushort_t Psh[4][16 * 68];    // 8.5 KB

    const int t = threadIdx.x;
    const int lane = t & 63;
    const int w = t >> 6;
    const int quad = lane >> 4;
    const int c = lane & 15;
    const int q4 = quad * 4;
    const int c7 = c & 7;

    const int head = blockIdx.x >> 4;     // b*NQ + h
    const int a = blockIdx.x & 15;
    const int h = head & (NQ - 1);
    const int b = head >> 4;
    const int kvh = b * NKV + (h >> 1);

    const ushort_t* Kg = K + (size_t)kvh * SEQ * HD;
    const ushort_t* Vg = V + (size_t)kvh * HD * SEQ;

    // staging address precompute (chunk id = t + 256*i)
    const ushort_t* gK[4]; const ushort_t* gV[4];
    int lo[4];
#pragma unroll
    for (int i = 0; i < 4; i++) {
        int cid = t + 256 * i;
        int kr = cid >> 4, kc = cid & 15;
        gK[i] = Kg + (size_t)kr * HD + ((kc ^ (kr & 7)) * 8);
        int vd = cid >> 3, vc = cid & 7;
        gV[i] = Vg + (size_t)vd * SEQ + ((vc ^ (vd & 7)) * 8);
        lo[i] = (i * 256 + (t & ~63)) * 8;
    }

#pragma unroll 1
    for (int half = 0; half < 2; half++) {
        const int qt = half ? (31 - a) : a;
        const int qb0 = qt * 64;
        const int myrow = qb0 + w * 16;       // wave's first q-row

        // Q fragments (A-operand), row = myrow + c
        const ushort_t* Qg = Q + ((size_t)head * SEQ + myrow + c) * HD;
        bf16x8 qf[4];
#pragma unroll
        for (int ch = 0; ch < 4; ch++)
            qf[ch] = *(const bf16x8*)(Qg + ch * 32 + quad * 8);

        f32x4 o[8];
#pragma unroll
        for (int i = 0; i < 8; i++) o[i] = (f32x4){0.f, 0.f, 0.f, 0.f};
        float lp[4] = {0.f, 0.f, 0.f, 0.f};

        const int ntiles = qt + 1;

        // prime tile 0 into buffer 0
#pragma unroll
        for (int i = 0; i < 4; i++) gload_lds16(gK[i], &Ks[0][lo[i]]);
#pragma unroll
        for (int i = 0; i < 4; i++) gload_lds16(gV[i], &Vs[0][lo[i]]);
        __syncthreads();

        for (int tile = 0; tile < ntiles; ++tile) {
            const int cur = tile & 1;
            if (tile + 1 < ntiles) {
                const int j1 = (tile + 1) * 64;
#pragma unroll
                for (int i = 0; i < 4; i++)
                    gload_lds16(gK[i] + (size_t)j1 * HD, &Ks[cur ^ 1][lo[i]]);
#pragma unroll
                for (int i = 0; i < 4; i++)
                    gload_lds16(gV[i] + j1, &Vs[cur ^ 1][lo[i]]);
            }

            // ---- QK^T
            f32x4 s[4];
#pragma unroll
            for (int tt = 0; tt < 4; tt++) s[tt] = (f32x4){0.f, 0.f, 0.f, 0.f};
#pragma unroll
            for (int tt = 0; tt < 4; tt++) {
                const int krow = tt * 16 + c;
#pragma unroll
                for (int ch = 0; ch < 4; ch++) {
                    bf16x8 kf = *(const bf16x8*)
                        &Ks[cur][krow * 128 + (((ch * 4 + quad) ^ c7) * 8)];
                    s[tt] = __builtin_amdgcn_mfma_f32_16x16x32_bf16(
                        qf[ch], kf, s[tt], 0, 0, 0);
                }
            }

            // ---- constant-max softmax: p = exp2(s*scale), masked -> 0
            const bool diag = (tile == qt);
            const int j0 = tile * 64;
#pragma unroll
            for (int r = 0; r < 4; r++) {
                const int row_g = myrow + q4 + r;
#pragma unroll
                for (int tt = 0; tt < 4; tt++) {
                    float p = exp2f(s[tt][r] * SM_SCALE);
                    if (diag && (j0 + tt * 16 + c > row_g)) p = 0.f;
                    Psh[w][(q4 + r) * 68 + tt * 16 + c] = f2bf(p);
                    lp[r] += p;
                }
            }

            // ---- P fragments (A-layout)
            bf16x8 pf[2];
#pragma unroll
            for (int ch = 0; ch < 2; ch++) {
                int base = c * 68 + ch * 32 + quad * 8;
                uint2 aa = *(const uint2*)&Psh[w][base];
                uint2 bb = *(const uint2*)&Psh[w][base + 4];
                uint4 u; u.x = aa.x; u.y = aa.y; u.z = bb.x; u.w = bb.y;
                pf[ch] = __builtin_bit_cast(bf16x8, u);
            }

            // ---- PV
#pragma unroll
            for (int dt = 0; dt < 8; dt++) {
                const int vrow = dt * 16 + c;
#pragma unroll
                for (int ch = 0; ch < 2; ch++) {
                    bf16x8 vf = *(const bf16x8*)
                        &Vs[cur][vrow * 64 + (((ch * 4 + quad) ^ c7) * 8)];
                    o[dt] = __builtin_amdgcn_mfma_f32_16x16x32_bf16(
                        pf[ch], vf, o[dt], 0, 0, 0);
                }
            }
            __syncthreads();   // next tile staged + everyone done with cur
        }

        // ---- epilogue: reduce l over the 16 c-lanes, normalize, store
        float inv[4];
#pragma unroll
        for (int r = 0; r < 4; r++) {
            float v = lp[r];
            v += __shfl_xor(v, 1);
            v += __shfl_xor(v, 2);
            v += __shfl_xor(v, 4);
            v += __shfl_xor(v, 8);
            inv[r] = 1.f / v;
        }
        size_t base = ((size_t)b * SEQ + myrow + q4) * (NQ * HD) + h * HD + c;
#pragma unroll
        for (int r = 0; r < 4; r++)
#pragma unroll
            for (int dt = 0; dt < 8; dt++)
                O[base + (size_t)r * (NQ * HD) + dt * 16] =
                    f2bf(o[dt][r] * inv[r]);
    }
}

// ---------------------------------------------------------------------------
// Launch
// ---------------------------------------------------------------------------
extern "C" void kernel_launch(void* const* d_in, const int* in_sizes, int n_in,
                              void* d_out, int out_size, void* d_ws, size_t ws_size,
                              hipStream_t stream)
{
    const float* x  = (const float*)d_in[0];
    const float* Wq = (const float*)d_in[1];
    const float* Wk = (const float*)d_in[2];
    const float* Wv = (const float*)d_in[3];
    const float* Wo = (const float*)d_in[4];
    const float* qA = (const float*)d_in[5];
    const float* qB = (const float*)d_in[6];
    const float* kA = (const float*)d_in[7];
    const float* kB = (const float*)d_in[8];
    const float* vA = (const float*)d_in[9];
    const float* vB = (const float*)d_in[10];
    const float* oA = (const float*)d_in[11];
    const float* oB = (const float*)d_in[12];
    float* out = (float*)d_out;
    float* ws = (float*)d_ws;

    const int M = BATCH * SEQ;           // 4096

    float* xa_q = ws;
    float* xa_k = ws + 32768;
    float* xa_v = ws + 65536;
    float* xa_o = ws + 98304;
    ushort_t* q_lin = (ushort_t*)(ws + 131072);    // bf16 4096x2048
    ushort_t* k_lin = (ushort_t*)(ws + 4325376);   // bf16 4096x1024
    ushort_t* v_lin = (ushort_t*)(ws + 6422528);   // bf16 4096x1024
    ushort_t* qb    = (ushort_t*)(ws + 8519680);   // bf16 [B][16][S][128]
    ushort_t* kb    = (ushort_t*)(ws + 12713984);  // bf16 [B][8][S][128]
    ushort_t* vtb   = (ushort_t*)(ws + 14811136);  // bf16 [B][8][128][S]
    ushort_t* xbf   = (ushort_t*)(ws + 16908288);  // bf16 4096x2048
    ushort_t* Wqb   = (ushort_t*)(ws + 21102592);
    ushort_t* Wkb   = (ushort_t*)(ws + 23199744);
    ushort_t* Wvb   = (ushort_t*)(ws + 24248320);
    ushort_t* Wob   = (ushort_t*)(ws + 25296896);
    ushort_t* attn_out = q_lin;          // q_lin consumed before attention

    // fused prologue: x cast || weight casts || xa q/k/v MFMA
    prep_fused<<<4096 + 6144 + 256, 256, 0, stream>>>(
        x, xbf, qA, kA, vA, xa_q, xa_k, xa_v,
        Wq, Wk, Wv, Wo, Wqb, Wkb, Wvb, Wob);

    // fused QKV projection: 256^2 tiles, deep pipeline, fused LoRA
    gemm_qkv256<<<dim3(M / 256, 16), 512, 0, stream>>>(
        xbf, Wqb, Wkb, Wvb, q_lin, k_lin, v_lin,
        xa_q, xa_k, xa_v, qB, kB, vB);

    // fused relayout: RoPE q,k  ||  V transpose
    reshape_fused<<<4096 + 1024, 256, 0, stream>>>(
        q_lin, k_lin, qb, kb, v_lin, vtb);

    // flash attention (uniform 33-tile blocks, 2 co-resident blocks/CU)
    attn_mfma3<<<512, 256, 0, stream>>>(qb, kb, vtb, attn_out);

    // o-LoRA A-projection (MFMA) + output projection with fused o-LoRA
    lora_o_mfma<<<256, 256, 0, stream>>>(attn_out, oA, xa_o);
    gemm_wo<<<dim3(M / 128, HIDDEN / 128), 256, 0, stream>>>(
        attn_out, Wob, out, xa_o, oB);
}

// Round 7
// 346.272 us; speedup vs baseline: 1.2558x; 1.0739x over previous
//
#include <hip/hip_runtime.h>
#include <hip/hip_bf16.h>
#include <cmath>

// Problem constants
#define HIDDEN 2048
#define SEQ 2048
#define BATCH 2
#define NQ 16
#define NKV 8
#define HD 128
#define RANKL 8
#define LORA_SCALE 2.0f
#define INV_SQRT_D 0.08838834764831845f
#define LOG2E 1.4426950408889634f
#define SM_SCALE (INV_SQRT_D * LOG2E)

typedef unsigned short ushort_t;
typedef __bf16 bf16x8 __attribute__((ext_vector_type(8)));
typedef float f32x4 __attribute__((ext_vector_type(4)));

static __device__ __forceinline__ ushort_t f2bf(float f) {
    __hip_bfloat16 h = __float2bfloat16(f);
    return *(ushort_t*)&h;
}
static __device__ __forceinline__ float bf2f(ushort_t u) {
    unsigned int v = ((unsigned int)u) << 16;
    return __builtin_bit_cast(float, v);
}
static __device__ __forceinline__ void gload_lds16(const ushort_t* g, ushort_t* l) {
    __builtin_amdgcn_global_load_lds(
        (const __attribute__((address_space(1))) unsigned int*)g,
        (__attribute__((address_space(3))) unsigned int*)l, 16, 0, 0);
}
static __device__ __forceinline__ bf16x8 pack8(float4 a, float4 b) {
    uint4 u;
    u.x = (unsigned int)f2bf(a.x) | ((unsigned int)f2bf(a.y) << 16);
    u.y = (unsigned int)f2bf(a.z) | ((unsigned int)f2bf(a.w) << 16);
    u.z = (unsigned int)f2bf(b.x) | ((unsigned int)f2bf(b.y) << 16);
    u.w = (unsigned int)f2bf(b.z) | ((unsigned int)f2bf(b.w) << 16);
    return __builtin_bit_cast(bf16x8, u);
}

// ---------------------------------------------------------------------------
// Fused prologue, GRID-STRIDE (2048 blocks; ~7.6ns/block dispatch cost made
// this kernel launch-bound at 10496 blocks -- R6 post-mortem).
// Units: [0,4096) x->bf16 cast row; [4096,10240) weight-cast chunk;
//        [10240,10496) xa strip via MFMA (16 rows, 4 waves split K, LDS red).
// ---------------------------------------------------------------------------
#define PREP_UNITS 10496
__global__ __launch_bounds__(256) void prep_fused(
    const float* __restrict__ X, ushort_t* __restrict__ Xbf,
    const float* __restrict__ qA, const float* __restrict__ kA,
    const float* __restrict__ vA,
    float* __restrict__ xa_q, float* __restrict__ xa_k,
    float* __restrict__ xa_v,
    const float* __restrict__ Wq, const float* __restrict__ Wk,
    const float* __restrict__ Wv, const float* __restrict__ Wo,
    ushort_t* __restrict__ Wqb, ushort_t* __restrict__ Wkb,
    ushort_t* __restrict__ Wvb, ushort_t* __restrict__ Wob)
{
    __shared__ f32x4 red[4][2][64];
    const int t = threadIdx.x;

    for (int bid = blockIdx.x; bid < PREP_UNITS; bid += gridDim.x) {
        if (bid < 4096) {
            // ---- x cast: one row per unit, 8 elems/thread
            int c0 = t * 8;
            const float* xr = X + (size_t)bid * HIDDEN + c0;
            float4 a = *(const float4*)xr;
            float4 b = *(const float4*)(xr + 4);
            uint4 o;
            o.x = (unsigned int)f2bf(a.x) | ((unsigned int)f2bf(a.y) << 16);
            o.y = (unsigned int)f2bf(a.z) | ((unsigned int)f2bf(a.w) << 16);
            o.z = (unsigned int)f2bf(b.x) | ((unsigned int)f2bf(b.y) << 16);
            o.w = (unsigned int)f2bf(b.z) | ((unsigned int)f2bf(b.w) << 16);
            *(uint4*)(Xbf + (size_t)bid * HIDDEN + c0) = o;
        } else if (bid < 10240) {
            // ---- weight casts
            size_t i = (size_t)(bid - 4096) * 256 + t;   // 0..1572863
            const float* src; ushort_t* dst; size_t j;
            if (i < 524288)       { src = Wq; dst = Wqb; j = i; }
            else if (i < 786432)  { src = Wk; dst = Wkb; j = i - 524288; }
            else if (i < 1048576) { src = Wv; dst = Wvb; j = i - 786432; }
            else                  { src = Wo; dst = Wob; j = i - 1048576; }
            const float4* p = (const float4*)src + j * 2;
            float4 a = p[0], b = p[1];
            uint4 o;
            o.x = (unsigned int)f2bf(a.x) | ((unsigned int)f2bf(a.y) << 16);
            o.y = (unsigned int)f2bf(a.z) | ((unsigned int)f2bf(a.w) << 16);
            o.z = (unsigned int)f2bf(b.x) | ((unsigned int)f2bf(b.y) << 16);
            o.w = (unsigned int)f2bf(b.z) | ((unsigned int)f2bf(b.w) << 16);
            *(uint4*)(dst + j * 8) = o;
        } else {
            // ---- xa MFMA: 16 rows, cols 0..23 = [qA(8); kA(8); vA(8)]
            const int m0 = (bid - 10240) * 16;
            const int lane = t & 63;
            const int w = t >> 6;
            const int c = lane & 15;
            const int quad = lane >> 4;

            const float* b0 = (c < 8) ? (qA + (size_t)c * HIDDEN)
                                      : (kA + (size_t)(c - 8) * HIDDEN);
            const float* b1 = vA + (size_t)(c & 7) * HIDDEN;
            const bool b1v = (c < 8);
            const float* ax = X + (size_t)(m0 + c) * HIDDEN;

            f32x4 acc0 = (f32x4){0.f, 0.f, 0.f, 0.f};
            f32x4 acc1 = (f32x4){0.f, 0.f, 0.f, 0.f};
            const int kbase = w * 512 + quad * 8;
#pragma unroll
            for (int ks = 0; ks < 16; ++ks) {
                const int k = kbase + ks * 32;
                float4 x0 = *(const float4*)&ax[k];
                float4 x1 = *(const float4*)&ax[k + 4];
                float4 p0a = *(const float4*)&b0[k];
                float4 p0b = *(const float4*)&b0[k + 4];
                float4 p1a = {0.f, 0.f, 0.f, 0.f}, p1b = {0.f, 0.f, 0.f, 0.f};
                if (b1v) { p1a = *(const float4*)&b1[k]; p1b = *(const float4*)&b1[k + 4]; }
                bf16x8 af = pack8(x0, x1);
                bf16x8 bf0 = pack8(p0a, p0b);
                bf16x8 bf1 = pack8(p1a, p1b);
                acc0 = __builtin_amdgcn_mfma_f32_16x16x32_bf16(af, bf0, acc0, 0, 0, 0);
                acc1 = __builtin_amdgcn_mfma_f32_16x16x32_bf16(af, bf1, acc1, 0, 0, 0);
            }
            red[w][0][lane] = acc0;
            red[w][1][lane] = acc1;
            __syncthreads();
            if (t < 64) {
#pragma unroll
                for (int nt = 0; nt < 2; ++nt) {
                    f32x4 s = red[0][nt][t];
#pragma unroll
                    for (int ww = 1; ww < 4; ++ww) {
                        f32x4 o = red[ww][nt][t];
                        s[0] += o[0]; s[1] += o[1]; s[2] += o[2]; s[3] += o[3];
                    }
                    int col = nt * 16 + (t & 15);
                    if (col < 24) {
                        float* dst = (col < 8) ? xa_q : (col < 16) ? xa_k : xa_v;
                        int cc = col & 7;
                        int row0 = m0 + (t >> 4) * 4;
#pragma unroll
                        for (int r = 0; r < 4; ++r)
                            dst[(size_t)(row0 + r) * RANKL + cc] = s[r];
                    }
                }
            }
            __syncthreads();   // red reuse guard for next unit
        }
    }
}

// ---------------------------------------------------------------------------
// o-LoRA A-projection via MFMA: xa_o = attn_out @ oA^T.
// 16 rows/block, 4 waves split K=2048, LDS reduce. A is bf16 (direct loads).
// ---------------------------------------------------------------------------
__global__ __launch_bounds__(256) void lora_o_mfma(
    const ushort_t* __restrict__ Xo, const float* __restrict__ oA,
    float* __restrict__ xa_o)
{
    __shared__ f32x4 red[4][64];
    const int t = threadIdx.x;
    const int lane = t & 63;
    const int w = t >> 6;
    const int c = lane & 15;
    const int quad = lane >> 4;
    const int m0 = blockIdx.x * 16;

    const ushort_t* ax = Xo + (size_t)(m0 + c) * (NQ * HD);
    const float* b0 = oA + (size_t)(c & 7) * (NQ * HD);
    const bool bv = (c < 8);

    f32x4 acc = (f32x4){0.f, 0.f, 0.f, 0.f};
    const int kbase = w * 512 + quad * 8;
#pragma unroll
    for (int ks = 0; ks < 16; ++ks) {
        const int k = kbase + ks * 32;
        bf16x8 af = *(const bf16x8*)&ax[k];
        float4 pa = {0.f, 0.f, 0.f, 0.f}, pb = {0.f, 0.f, 0.f, 0.f};
        if (bv) { pa = *(const float4*)&b0[k]; pb = *(const float4*)&b0[k + 4]; }
        bf16x8 bf = pack8(pa, pb);
        acc = __builtin_amdgcn_mfma_f32_16x16x32_bf16(af, bf, acc, 0, 0, 0);
    }
    red[w][lane] = acc;
    __syncthreads();
    if (t < 64) {
        f32x4 s = red[0][t];
#pragma unroll
        for (int ww = 1; ww < 4; ++ww) {
            f32x4 o = red[ww][t];
            s[0] += o[0]; s[1] += o[1]; s[2] += o[2]; s[3] += o[3];
        }
        int col = t & 15;
        if (col < 8) {
            int row0 = m0 + (t >> 4) * 4;
#pragma unroll
            for (int r = 0; r < 4; ++r)
                xa_o[(size_t)(row0 + r) * RANKL + col] = s[r];
        }
    }
}

// ---------------------------------------------------------------------------
// bf16 MFMA GEMM core (m97 structure, 128x128 tile) -- kept for gemm_wo.
// ---------------------------------------------------------------------------
static __device__ __forceinline__ void gemm_core(
    const ushort_t* __restrict__ A, const ushort_t* __restrict__ B,
    void* __restrict__ Cout, int N, int K, int bm, int bn,
    const float* __restrict__ xa, const float* __restrict__ LB,
    float lscale, int out_bf16, ushort_t* As, ushort_t* Bs)
{
    const int t = threadIdx.x;
    const int lane = t & 63;
    const int w = t >> 6;
    const int quad = lane >> 4;
    const int c = lane & 15;

    const int wm = (w & 1) * 64;
    const int wn = (w >> 1) * 64;

    f32x4 acc[4][4];
#pragma unroll
    for (int i = 0; i < 4; i++)
#pragma unroll
        for (int j = 0; j < 4; j++) acc[i][j] = (f32x4){0.f, 0.f, 0.f, 0.f};

    const int p0 = w * 64 + lane;
    const int p1 = 256 + w * 64 + lane;
    const int r0 = p0 >> 2, g0 = (p0 & 3) ^ ((p0 >> 3) & 3);
    const int r1 = p1 >> 2, g1 = (p1 & 3) ^ ((p1 >> 3) & 3);
    const ushort_t* gA0 = A + (size_t)(bm + r0) * K + g0 * 8;
    const ushort_t* gA1 = A + (size_t)(bm + r1) * K + g1 * 8;
    const ushort_t* gB0 = B + (size_t)(bn + r0) * K + g0 * 8;
    const ushort_t* gB1 = B + (size_t)(bn + r1) * K + g1 * 8;
    ushort_t* lA0 = As + (size_t)(w * 64) * 8;
    ushort_t* lA1 = As + (size_t)(256 + w * 64) * 8;
    ushort_t* lB0 = Bs + (size_t)(w * 64) * 8;
    ushort_t* lB1 = Bs + (size_t)(256 + w * 64) * 8;

    const int csw = quad ^ ((c >> 1) & 3);

    for (int k0 = 0; k0 < K; k0 += 32) {
        __syncthreads();
        gload_lds16(gA0 + k0, lA0);
        gload_lds16(gA1 + k0, lA1);
        gload_lds16(gB0 + k0, lB0);
        gload_lds16(gB1 + k0, lB1);
        __syncthreads();

        bf16x8 af[4], bfr[4];
#pragma unroll
        for (int mt = 0; mt < 4; mt++)
            af[mt] = *(const bf16x8*)&As[((wm + mt * 16 + c) * 4 + csw) * 8];
#pragma unroll
        for (int nt = 0; nt < 4; nt++)
            bfr[nt] = *(const bf16x8*)&Bs[((wn + nt * 16 + c) * 4 + csw) * 8];
#pragma unroll
        for (int mt = 0; mt < 4; mt++)
#pragma unroll
            for (int nt = 0; nt < 4; nt++)
                acc[mt][nt] = __builtin_amdgcn_mfma_f32_16x16x32_bf16(
                    af[mt], bfr[nt], acc[mt][nt], 0, 0, 0);
    }

    float lb[4][RANKL];
#pragma unroll
    for (int nt = 0; nt < 4; nt++) {
        int col = bn + wn + nt * 16 + c;
        float4 u = *(const float4*)&LB[(size_t)col * RANKL];
        float4 v = *(const float4*)&LB[(size_t)col * RANKL + 4];
        lb[nt][0] = u.x; lb[nt][1] = u.y; lb[nt][2] = u.z; lb[nt][3] = u.w;
        lb[nt][4] = v.x; lb[nt][5] = v.y; lb[nt][6] = v.z; lb[nt][7] = v.w;
    }
#pragma unroll
    for (int mt = 0; mt < 4; mt++) {
        float la[4][RANKL];
#pragma unroll
        for (int r = 0; r < 4; r++) {
            int row = bm + wm + mt * 16 + quad * 4 + r;
            float4 u = *(const float4*)&xa[(size_t)row * RANKL];
            float4 v = *(const float4*)&xa[(size_t)row * RANKL + 4];
            la[r][0] = u.x; la[r][1] = u.y; la[r][2] = u.z; la[r][3] = u.w;
            la[r][4] = v.x; la[r][5] = v.y; la[r][6] = v.z; la[r][7] = v.w;
        }
#pragma unroll
        for (int nt = 0; nt < 4; nt++) {
#pragma unroll
            for (int r = 0; r < 4; r++) {
                float s = 0.f;
#pragma unroll
                for (int k = 0; k < RANKL; k++) s += la[r][k] * lb[nt][k];
                float val = acc[mt][nt][r] + lscale * s;
                size_t row = bm + wm + mt * 16 + quad * 4 + r;
                size_t col = bn + wn + nt * 16 + c;
                if (out_bf16)
                    ((ushort_t*)Cout)[row * N + col] = f2bf(val);
                else
                    ((float*)Cout)[row * N + col] = val;
            }
        }
    }
}

// ---------------------------------------------------------------------------
// 256x256-tile 8-wave deep-pipelined QKV GEMM (T2+T3+T4+T5).
// ---------------------------------------------------------------------------
#define BKT 64
#define NKT (HIDDEN / BKT)   // 32

__global__ __launch_bounds__(512, 2) void gemm_qkv256(
    const ushort_t* __restrict__ A,
    const ushort_t* __restrict__ Wqb, const ushort_t* __restrict__ Wkb,
    const ushort_t* __restrict__ Wvb,
    ushort_t* __restrict__ q_lin, ushort_t* __restrict__ k_lin,
    ushort_t* __restrict__ v_lin,
    const float* __restrict__ xa_q, const float* __restrict__ xa_k,
    const float* __restrict__ xa_v,
    const float* __restrict__ qB, const float* __restrict__ kB,
    const float* __restrict__ vB)
{
    __shared__ __align__(16) ushort_t As[2][256 * BKT];   // 64 KiB
    __shared__ __align__(16) ushort_t Bs[2][256 * BKT];   // 64 KiB

    const int t = threadIdx.x;
    const int lane = t & 63;
    const int w = t >> 6;          // 0..7
    const int wm = w >> 2;         // 0..1  (M half)
    const int wn = w & 3;          // 0..3  (N quarter)
    const int quad = lane >> 4;
    const int c = lane & 15;
    const int c7 = c & 7;

    const int bc = blockIdx.y;
    const ushort_t* Bmat; ushort_t* Cout; const float* xa; const float* LB;
    int N, bn;
    if (bc < 8)       { Bmat = Wqb; Cout = q_lin; xa = xa_q; LB = qB; N = 2048; bn = bc * 256; }
    else if (bc < 12) { Bmat = Wkb; Cout = k_lin; xa = xa_k; LB = kB; N = 1024; bn = (bc - 8) * 256; }
    else              { Bmat = Wvb; Cout = v_lin; xa = xa_v; LB = vB; N = 1024; bn = (bc - 12) * 256; }
    const int bm = blockIdx.x * 256;

    // ---- staging addressing (chunk-XOR involution, linear LDS dest)
    const int r8  = lane >> 3;           // 0..7 row within 8-row group
    const int ksl = (lane & 7) ^ r8;     // swizzled k-chunk for this lane
    const int ga  = wn;                  // index within A staging group (wm)
    const int bh  = wn >> 1;             // B half this wave consumes
    const int gb  = wm * 2 + (wn & 1);   // index within B staging group (bh)

    const ushort_t* gAb = A    + (size_t)(bm + wm * 128 + ga * 8 + r8) * HIDDEN + ksl * 8;
    const ushort_t* gBb = Bmat + (size_t)(bn + bh * 128 + gb * 8 + r8) * HIDDEN + ksl * 8;
    const int lAoff = (wm * 128 + ga * 8) * BKT;   // + j*32*BKT
    const int lBoff = (bh * 128 + gb * 8) * BKT;

    // ---- prologue: tile 0 fully, tile 1 parts j=0..2
#pragma unroll
    for (int j = 0; j < 4; j++) {
        gload_lds16(gAb + (size_t)j * 32 * HIDDEN, &As[0][lAoff + j * 32 * BKT]);
        gload_lds16(gBb + (size_t)j * 32 * HIDDEN, &Bs[0][lBoff + j * 32 * BKT]);
    }
#pragma unroll
    for (int j = 0; j < 3; j++) {
        gload_lds16(gAb + (size_t)j * 32 * HIDDEN + BKT, &As[1][lAoff + j * 32 * BKT]);
        gload_lds16(gBb + (size_t)j * 32 * HIDDEN + BKT, &Bs[1][lBoff + j * 32 * BKT]);
    }

    f32x4 acc[8][4];
#pragma unroll
    for (int i = 0; i < 8; i++)
#pragma unroll
        for (int j = 0; j < 4; j++) acc[i][j] = (f32x4){0.f, 0.f, 0.f, 0.f};

#pragma unroll 1
    for (int T = 0; T < NKT; ++T) {
        const int cur = T & 1;
        const ushort_t* cA = As[cur];
        const ushort_t* cB = Bs[cur];
        bf16x8 bfr[4][2];

#pragma unroll
        for (int q = 0; q < 4; ++q) {
            if (q == 0) {
                asm volatile("s_waitcnt vmcnt(6)" ::: "memory");
            }
            __builtin_amdgcn_sched_barrier(0);
            __builtin_amdgcn_s_barrier();
            __builtin_amdgcn_sched_barrier(0);

            // ---- ds reads: A quadrant q (4 x b128); B all (8 x b128) at q==0
            bf16x8 af[2][2];
#pragma unroll
            for (int m2 = 0; m2 < 2; ++m2) {
                const int row = wm * 128 + (q * 2 + m2) * 16 + c;
#pragma unroll
                for (int kh = 0; kh < 2; ++kh)
                    af[m2][kh] = *(const bf16x8*)
                        &cA[row * BKT + (((kh * 4 + quad) ^ c7) * 8)];
            }
            if (q == 0) {
#pragma unroll
                for (int nt = 0; nt < 4; ++nt) {
                    const int rowb = wn * 64 + nt * 16 + c;
#pragma unroll
                    for (int kh = 0; kh < 2; ++kh)
                        bfr[nt][kh] = *(const bf16x8*)
                            &cB[rowb * BKT + (((kh * 4 + quad) ^ c7) * 8)];
                }
            }

            // ---- staging
            if (q == 0) {
                const int tl = T + 1;
                if (tl < NKT) {
                    gload_lds16(gAb + (size_t)3 * 32 * HIDDEN + (size_t)tl * BKT,
                                &As[cur ^ 1][lAoff + 3 * 32 * BKT]);
                    gload_lds16(gBb + (size_t)3 * 32 * HIDDEN + (size_t)tl * BKT,
                                &Bs[cur ^ 1][lBoff + 3 * 32 * BKT]);
                }
            } else {
                const int tl = T + 2;
                if (tl < NKT) {
                    const int j = q - 1;
                    gload_lds16(gAb + (size_t)j * 32 * HIDDEN + (size_t)tl * BKT,
                                &As[cur][lAoff + j * 32 * BKT]);
                    gload_lds16(gBb + (size_t)j * 32 * HIDDEN + (size_t)tl * BKT,
                                &Bs[cur][lBoff + j * 32 * BKT]);
                }
            }

            // ---- 16 MFMA: C-quadrant (32 rows x 64 cols) over K=64
            __builtin_amdgcn_s_setprio(1);
#pragma unroll
            for (int m2 = 0; m2 < 2; ++m2)
#pragma unroll
                for (int nt = 0; nt < 4; ++nt)
#pragma unroll
                    for (int kh = 0; kh < 2; ++kh)
                        acc[q * 2 + m2][nt] = __builtin_amdgcn_mfma_f32_16x16x32_bf16(
                            af[m2][kh], bfr[nt][kh], acc[q * 2 + m2][nt], 0, 0, 0);
            __builtin_amdgcn_s_setprio(0);
        }
    }

    // ---- epilogue: fused LoRA rank-8 + bf16 store
    float lb[4][RANKL];
#pragma unroll
    for (int nt = 0; nt < 4; nt++) {
        int col = bn + wn * 64 + nt * 16 + c;
        float4 u = *(const float4*)&LB[(size_t)col * RANKL];
        float4 v = *(const float4*)&LB[(size_t)col * RANKL + 4];
        lb[nt][0] = u.x; lb[nt][1] = u.y; lb[nt][2] = u.z; lb[nt][3] = u.w;
        lb[nt][4] = v.x; lb[nt][5] = v.y; lb[nt][6] = v.z; lb[nt][7] = v.w;
    }
#pragma unroll
    for (int mt = 0; mt < 8; mt++) {
        float la[4][RANKL];
#pragma unroll
        for (int r = 0; r < 4; r++) {
            int row = bm + wm * 128 + mt * 16 + quad * 4 + r;
            float4 u = *(const float4*)&xa[(size_t)row * RANKL];
            float4 v = *(const float4*)&xa[(size_t)row * RANKL + 4];
            la[r][0] = u.x; la[r][1] = u.y; la[r][2] = u.z; la[r][3] = u.w;
            la[r][4] = v.x; la[r][5] = v.y; la[r][6] = v.z; la[r][7] = v.w;
        }
#pragma unroll
        for (int nt = 0; nt < 4; nt++) {
#pragma unroll
            for (int r = 0; r < 4; r++) {
                float s = 0.f;
#pragma unroll
                for (int k = 0; k < RANKL; k++) s += la[r][k] * lb[nt][k];
                float val = acc[mt][nt][r] + LORA_SCALE * s;
                size_t row = bm + wm * 128 + mt * 16 + quad * 4 + r;
                size_t col = bn + wn * 64 + nt * 16 + c;
                Cout[row * N + col] = f2bf(val);
            }
        }
    }
}

// Output projection (fp32 out) -- m97-structure core (known-good)
__global__ __launch_bounds__(256) void gemm_wo(
    const ushort_t* __restrict__ A, const ushort_t* __restrict__ Wob,
    float* __restrict__ out, const float* __restrict__ xa_o,
    const float* __restrict__ oB)
{
    __shared__ ushort_t As[128 * 32];
    __shared__ ushort_t Bs[128 * 32];
    gemm_core(A, Wob, out, HIDDEN, NQ * HD, blockIdx.x * 128, blockIdx.y * 128,
              xa_o, oB, LORA_SCALE, 0, As, Bs);
}

// ---------------------------------------------------------------------------
// Fused relayout, GRID-STRIDE (2048 blocks).
// Units: [0,4096) RoPE row; [4096,5120) V-transpose 64x64 tile.
// ---------------------------------------------------------------------------
#define RESHAPE_UNITS 5120
__global__ __launch_bounds__(256) void reshape_fused(
    const ushort_t* __restrict__ qlin, const ushort_t* __restrict__ klin,
    ushort_t* __restrict__ qb, ushort_t* __restrict__ kb,
    const ushort_t* __restrict__ vlin, ushort_t* __restrict__ Vt)
{
    __shared__ ushort_t tile[64 * 72];
    int t = threadIdx.x;
    for (int bid = blockIdx.x; bid < RESHAPE_UNITS; bid += gridDim.x) {
        if (bid < 4096) {
            int bs = bid;
            int s = bs & (SEQ - 1);
            int b = bs >> 11;
            int p = t & 63;
            float inv = exp2f(-(float)p * 0.20762050593046f); // 10000^(-p/64)
            float ang = (float)s * inv;
            float cc = cosf(ang), si = sinf(ang);
#pragma unroll
            for (int j = 0; j < 6; j++) {
                int item = t + 256 * j;
                int hh = item >> 6;       // 0..23
                unsigned int pk;
                ushort_t* dst;
                if (hh < NQ) {
                    pk = *(const unsigned int*)&qlin[(size_t)bs * (NQ * HD) + hh * HD + 2 * p];
                    dst = qb + (((size_t)(b * NQ + hh) * SEQ) + s) * HD + 2 * p;
                } else {
                    int kh = hh - NQ;
                    pk = *(const unsigned int*)&klin[(size_t)bs * (NKV * HD) + kh * HD + 2 * p];
                    dst = kb + (((size_t)(b * NKV + kh) * SEQ) + s) * HD + 2 * p;
                }
                float xr = bf2f((ushort_t)(pk & 0xffff));
                float xi = bf2f((ushort_t)(pk >> 16));
                float rr = xr * cc - xi * si;
                float ri = xr * si + xi * cc;
                *(unsigned int*)dst = ((unsigned int)f2bf(ri) << 16) | f2bf(rr);
            }
        } else {
            int idx = bid - 4096;              // 0..1023
            int bk = idx >> 6;                 // 0..15 (b*8+kvh)
            int rem = idx & 63;
            int b = bk >> 3, kvh = bk & 7;
            int s0 = (rem >> 1) * 64, d0 = (rem & 1) * 64;
#pragma unroll
            for (int i = 0; i < 2; i++) {
                int id = t + 256 * i;
                int r = id >> 3, cc = id & 7;
                uint4 v = *(const uint4*)&vlin[(size_t)(b * SEQ + s0 + r) * (NKV * HD)
                                               + kvh * HD + d0 + cc * 8];
                *(uint4*)&tile[r * 72 + cc * 8] = v;
            }
            __syncthreads();
#pragma unroll
            for (int i = 0; i < 2; i++) {
                int id = t + 256 * i;
                int dr = id >> 3, sc = id & 7;
                ushort_t tmp[8];
#pragma unroll
                for (int e = 0; e < 8; e++) tmp[e] = tile[(sc * 8 + e) * 72 + dr];
                *(uint4*)&Vt[((size_t)(b * NKV + kvh) * HD + d0 + dr) * SEQ + s0 + sc * 8]
                    = *(uint4*)tmp;
            }
            __syncthreads();   // tile reuse guard for next unit
        }
    }
}

// ---------------------------------------------------------------------------
// MFMA flash attention v3 (BEST measured: 78.8 us).
// Block = 4 waves; handles q-tiles {a, 31-a} (64 rows each) sequentially ->
// exactly 33 key-tiles per block (uniform). Constant-max softmax. Ping-pong
// K/V staging, ONE barrier per tile. 512 blocks -> 2 co-resident uniform
// blocks per CU (sequential pairing keeps both alive to the end).
// Q,K: [b][h][s][128]; V: [b][kvh][d][s]; O: bf16 [b*s][h*128+d].
// ---------------------------------------------------------------------------
__global__ __launch_bounds__(256, 2) void attn_mfma3(
    const ushort_t* __restrict__ Q, const ushort_t* __restrict__ K,
    const ushort_t* __restrict__ V, ushort_t* __restrict__ O)
{
    __shared__ ushort_t Ks[2][64 * 128];    // 16 KB x2
    __shared__ ushort_t Vs[2][128 * 64];    // 16 KB x2
    __shared__ ushort_t Psh[4][16 * 68];    // 8.5 KB

    const int t = threadIdx.x;
    const int lane = t & 63;
    const int w = t >> 6;
    const int quad = lane >> 4;
    const int c = lane & 15;
    const int q4 = quad * 4;
    const int c7 = c & 7;

    const int head = blockIdx.x >> 4;     // b*NQ + h
    const int a = blockIdx.x & 15;
    const int h = head & (NQ - 1);
    const int b = head >> 4;
    const int kvh = b * NKV + (h >> 1);

    const ushort_t* Kg = K + (size_t)kvh * SEQ * HD;
    const ushort_t* Vg = V + (size_t)kvh * HD * SEQ;

    // staging address precompute (chunk id = t + 256*i)
    const ushort_t* gK[4]; const ushort_t* gV[4];
    int lo[4];
#pragma unroll
    for (int i = 0; i < 4; i++) {
        int cid = t + 256 * i;
        int kr = cid >> 4, kc = cid & 15;
        gK[i] = Kg + (size_t)kr * HD + ((kc ^ (kr & 7)) * 8);
        int vd = cid >> 3, vc = cid & 7;
        gV[i] = Vg + (size_t)vd * SEQ + ((vc ^ (vd & 7)) * 8);
        lo[i] = (i * 256 + (t & ~63)) * 8;
    }

#pragma unroll 1
    for (int half = 0; half < 2; half++) {
        const int qt = half ? (31 - a) : a;
        const int qb0 = qt * 64;
        const int myrow = qb0 + w * 16;       // wave's first q-row

        // Q fragments (A-operand), row = myrow + c
        const ushort_t* Qg = Q + ((size_t)head * SEQ + myrow + c) * HD;
        bf16x8 qf[4];
#pragma unroll
        for (int ch = 0; ch < 4; ch++)
            qf[ch] = *(const bf16x8*)(Qg + ch * 32 + quad * 8);

        f32x4 o[8];
#pragma unroll
        for (int i = 0; i < 8; i++) o[i] = (f32x4){0.f, 0.f, 0.f, 0.f};
        float lp[4] = {0.f, 0.f, 0.f, 0.f};

        const int ntiles = qt + 1;

        // prime tile 0 into buffer 0
#pragma unroll
        for (int i = 0; i < 4; i++) gload_lds16(gK[i], &Ks[0][lo[i]]);
#pragma unroll
        for (int i = 0; i < 4; i++) gload_lds16(gV[i], &Vs[0][lo[i]]);
        __syncthreads();

        for (int tile = 0; tile < ntiles; ++tile) {
            const int cur = tile & 1;
            if (tile + 1 < ntiles) {
                const int j1 = (tile + 1) * 64;
#pragma unroll
                for (int i = 0; i < 4; i++)
                    gload_lds16(gK[i] + (size_t)j1 * HD, &Ks[cur ^ 1][lo[i]]);
#pragma unroll
                for (int i = 0; i < 4; i++)
                    gload_lds16(gV[i] + j1, &Vs[cur ^ 1][lo[i]]);
            }

            // ---- QK^T
            f32x4 s[4];
#pragma unroll
            for (int tt = 0; tt < 4; tt++) s[tt] = (f32x4){0.f, 0.f, 0.f, 0.f};
#pragma unroll
            for (int tt = 0; tt < 4; tt++) {
                const int krow = tt * 16 + c;
#pragma unroll
                for (int ch = 0; ch < 4; ch++) {
                    bf16x8 kf = *(const bf16x8*)
                        &Ks[cur][krow * 128 + (((ch * 4 + quad) ^ c7) * 8)];
                    s[tt] = __builtin_amdgcn_mfma_f32_16x16x32_bf16(
                        qf[ch], kf, s[tt], 0, 0, 0);
                }
            }

            // ---- constant-max softmax: p = exp2(s*scale), masked -> 0
            const bool diag = (tile == qt);
            const int j0 = tile * 64;
#pragma unroll
            for (int r = 0; r < 4; r++) {
                const int row_g = myrow + q4 + r;
#pragma unroll
                for (int tt = 0; tt < 4; tt++) {
                    float p = exp2f(s[tt][r] * SM_SCALE);
                    if (diag && (j0 + tt * 16 + c > row_g)) p = 0.f;
                    Psh[w][(q4 + r) * 68 + tt * 16 + c] = f2bf(p);
                    lp[r] += p;
                }
            }

            // ---- P fragments (A-layout)
            bf16x8 pf[2];
#pragma unroll
            for (int ch = 0; ch < 2; ch++) {
                int base = c * 68 + ch * 32 + quad * 8;
                uint2 aa = *(const uint2*)&Psh[w][base];
                uint2 bb = *(const uint2*)&Psh[w][base + 4];
                uint4 u; u.x = aa.x; u.y = aa.y; u.z = bb.x; u.w = bb.y;
                pf[ch] = __builtin_bit_cast(bf16x8, u);
            }

            // ---- PV
#pragma unroll
            for (int dt = 0; dt < 8; dt++) {
                const int vrow = dt * 16 + c;
#pragma unroll
                for (int ch = 0; ch < 2; ch++) {
                    bf16x8 vf = *(const bf16x8*)
                        &Vs[cur][vrow * 64 + (((ch * 4 + quad) ^ c7) * 8)];
                    o[dt] = __builtin_amdgcn_mfma_f32_16x16x32_bf16(
                        pf[ch], vf, o[dt], 0, 0, 0);
                }
            }
            __syncthreads();   // next tile staged + everyone done with cur
        }

        // ---- epilogue: reduce l over the 16 c-lanes, normalize, store
        float inv[4];
#pragma unroll
        for (int r = 0; r < 4; r++) {
            float v = lp[r];
            v += __shfl_xor(v, 1);
            v += __shfl_xor(v, 2);
            v += __shfl_xor(v, 4);
            v += __shfl_xor(v, 8);
            inv[r] = 1.f / v;
        }
        size_t base = ((size_t)b * SEQ + myrow + q4) * (NQ * HD) + h * HD + c;
#pragma unroll
        for (int r = 0; r < 4; r++)
#pragma unroll
            for (int dt = 0; dt < 8; dt++)
                O[base + (size_t)r * (NQ * HD) + dt * 16] =
                    f2bf(o[dt][r] * inv[r]);
    }
}

// ---------------------------------------------------------------------------
// Launch
// ---------------------------------------------------------------------------
extern "C" void kernel_launch(void* const* d_in, const int* in_sizes, int n_in,
                              void* d_out, int out_size, void* d_ws, size_t ws_size,
                              hipStream_t stream)
{
    const float* x  = (const float*)d_in[0];
    const float* Wq = (const float*)d_in[1];
    const float* Wk = (const float*)d_in[2];
    const float* Wv = (const float*)d_in[3];
    const float* Wo = (const float*)d_in[4];
    const float* qA = (const float*)d_in[5];
    const float* qB = (const float*)d_in[6];
    const float* kA = (const float*)d_in[7];
    const float* kB = (const float*)d_in[8];
    const float* vA = (const float*)d_in[9];
    const float* vB = (const float*)d_in[10];
    const float* oA = (const float*)d_in[11];
    const float* oB = (const float*)d_in[12];
    float* out = (float*)d_out;
    float* ws = (float*)d_ws;

    const int M = BATCH * SEQ;           // 4096

    float* xa_q = ws;
    float* xa_k = ws + 32768;
    float* xa_v = ws + 65536;
    float* xa_o = ws + 98304;
    ushort_t* q_lin = (ushort_t*)(ws + 131072);    // bf16 4096x2048
    ushort_t* k_lin = (ushort_t*)(ws + 4325376);   // bf16 4096x1024
    ushort_t* v_lin = (ushort_t*)(ws + 6422528);   // bf16 4096x1024
    ushort_t* qb    = (ushort_t*)(ws + 8519680);   // bf16 [B][16][S][128]
    ushort_t* kb    = (ushort_t*)(ws + 12713984);  // bf16 [B][8][S][128]
    ushort_t* vtb   = (ushort_t*)(ws + 14811136);  // bf16 [B][8][128][S]
    ushort_t* xbf   = (ushort_t*)(ws + 16908288);  // bf16 4096x2048
    ushort_t* Wqb   = (ushort_t*)(ws + 21102592);
    ushort_t* Wkb   = (ushort_t*)(ws + 23199744);
    ushort_t* Wvb   = (ushort_t*)(ws + 24248320);
    ushort_t* Wob   = (ushort_t*)(ws + 25296896);
    ushort_t* attn_out = q_lin;          // q_lin consumed before attention

    // fused prologue (grid-stride, 2048 blocks): x cast || weight casts || xa MFMA
    prep_fused<<<2048, 256, 0, stream>>>(
        x, xbf, qA, kA, vA, xa_q, xa_k, xa_v,
        Wq, Wk, Wv, Wo, Wqb, Wkb, Wvb, Wob);

    // fused QKV projection: 256^2 tiles, deep pipeline, fused LoRA
    gemm_qkv256<<<dim3(M / 256, 16), 512, 0, stream>>>(
        xbf, Wqb, Wkb, Wvb, q_lin, k_lin, v_lin,
        xa_q, xa_k, xa_v, qB, kB, vB);

    // fused relayout (grid-stride, 2048 blocks): RoPE q,k || V transpose
    reshape_fused<<<2048, 256, 0, stream>>>(
        q_lin, k_lin, qb, kb, v_lin, vtb);

    // flash attention (uniform 33-tile blocks, 2 co-resident blocks/CU)
    attn_mfma3<<<512, 256, 0, stream>>>(qb, kb, vtb, attn_out);

    // o-LoRA A-projection (MFMA) + output projection with fused o-LoRA
    lora_o_mfma<<<256, 256, 0, stream>>>(attn_out, oA, xa_o);
    gemm_wo<<<dim3(M / 128, HIDDEN / 128), 256, 0, stream>>>(
        attn_out, Wob, out, xa_o, oB);
}